// Round 2
// baseline (2664.843 us; speedup 1.0000x reference)
//
#include <hip/hip_runtime.h>
#include <hip/hip_bf16.h>
#include <math.h>

#define NN 10000
#define NE 160000
#define NF 128
#define NB 20
#define CUT 5.0f

// ---------------- dtype detector: 1=bf16, 0=fp32 ----------------
// Inspect me_W (7680 elements, Gaussian sigma~0.22) as halfwords.
// True bf16: ~100% decode to |v| in [6e-8, 16]. fp32: even halfwords are
// raw mantissa bits -> ~55% plausible. Threshold 90%.
__global__ __launch_bounds__(256) void k_detect(const void* __restrict__ w, int nelem,
                                                int* __restrict__ flag){
  __shared__ int cnt;
  if (threadIdx.x == 0) cnt = 0;
  __syncthreads();
  const unsigned short* hw = (const unsigned short*)w;
  int local = 0;
  for (int k = threadIdx.x; k < nelem; k += 256){
    unsigned short h = hw[k];
    int e = (h >> 7) & 0xFF;
    if ((h & 0x7FFF) == 0 || (e >= 103 && e <= 130)) local++;
  }
  atomicAdd(&cnt, local);
  __syncthreads();
  if (threadIdx.x == 0) *flag = (cnt >= (nelem * 9) / 10) ? 1 : 0;
}

// ---------------- generic convert-to-fp32 ----------------
__global__ __launch_bounds__(256) void k_cvt(const void* __restrict__ src, float* __restrict__ dst,
                                             int n, const int* __restrict__ flag){
  int i = blockIdx.x * 256 + threadIdx.x;
  if (i >= n) return;
  int isb = *flag;
  dst[i] = isb ? __bfloat162float(((const __hip_bfloat16*)src)[i])
               : ((const float*)src)[i];
}

// ---------------- init: atom = node_emb[z] ----------------
__global__ __launch_bounds__(256) void k_init_atom(const int* __restrict__ z,
                                                   const float* __restrict__ emb,
                                                   float* __restrict__ atom){
  int idx = blockIdx.x * 256 + threadIdx.x;
  if (idx >= NN * NF) return;
  int n = idx >> 7, f = idx & (NF - 1);
  atom[idx] = emb[z[n] * NF + f];
}

// ---------------- edge embedding: d (E,), dir (E,3) ----------------
__global__ __launch_bounds__(256) void k_edge_embed(const int* __restrict__ ei,
                                                    const float* __restrict__ pos,
                                                    float* __restrict__ dvals,
                                                    float* __restrict__ dirv){
  int e = blockIdx.x * 256 + threadIdx.x;
  if (e >= NE) return;
  int i = ei[e], j = ei[NE + e];
  float dx = pos[j*3+0] - pos[i*3+0];
  float dy = pos[j*3+1] - pos[i*3+1];
  float dz = pos[j*3+2] - pos[i*3+2];
  float d = sqrtf(dx*dx + dy*dy + dz*dz + 1e-12f);
  float inv = 1.0f / d;
  dvals[e] = d;
  dirv[e*3+0] = dx*inv; dirv[e*3+1] = dy*inv; dirv[e*3+2] = dz*inv;
}

// ---------------- node MLP: out = (silu?)(in @ W + b); 16 nodes/block ----------------
__global__ __launch_bounds__(128) void k_node_mlp(const float* __restrict__ in,
                                                  const float* __restrict__ W,
                                                  const float* __restrict__ b,
                                                  float* __restrict__ out, int apply_silu){
  __shared__ float a_lds[16][NF];
  int f = threadIdx.x;
  int n0 = blockIdx.x * 16;
  #pragma unroll
  for (int nn = 0; nn < 16; nn++){
    int n = n0 + nn;
    a_lds[nn][f] = (n < NN) ? in[n*NF + f] : 0.f;
  }
  __syncthreads();
  float acc[16];
  #pragma unroll
  for (int nn = 0; nn < 16; nn++) acc[nn] = 0.f;
  #pragma unroll 4
  for (int k = 0; k < NF; k++){
    float w = W[k*NF + f];
    #pragma unroll
    for (int nn = 0; nn < 16; nn++) acc[nn] += a_lds[nn][k] * w;
  }
  float bias = b[f];
  #pragma unroll
  for (int nn = 0; nn < 16; nn++){
    int n = n0 + nn;
    if (n < NN){
      float v = acc[nn] + bias;
      if (apply_silu) v = v / (1.f + expf(-v));
      out[n*NF + f] = v;
    }
  }
}

// ---------------- edge kernel ----------------
__global__ __launch_bounds__(128) void k_edge(
    const int* __restrict__ ei, const float* __restrict__ dvals, const float* __restrict__ dirv,
    const float* __restrict__ h, const float* __restrict__ meW,
    const float* __restrict__ w11, const float* __restrict__ w12,
    const float* __restrict__ w21, const float* __restrict__ w22,
    float* __restrict__ atom, const float* __restrict__ force, float* __restrict__ fdelta){
  __shared__ float msg_lds[16][NF];
  __shared__ float t_lds[16][NF];
  __shared__ int   iiL[16], jjL[16];
  __shared__ float dirL[16][3];
  __shared__ float dL[16];
  __shared__ float rbfL[16][NB];
  int f = threadIdx.x;
  int e0 = blockIdx.x * 16;   // grid = NE/16 exactly; all e valid

  if (f < 16){
    int e = e0 + f;
    iiL[f] = ei[e]; jjL[f] = ei[NE + e];
    dL[f] = dvals[e];
  }
  for (int t = f; t < 48; t += 128){
    int ee = t / 3, dd = t % 3;
    dirL[ee][dd] = dirv[(e0 + ee)*3 + dd];
  }
  __syncthreads();
  // rbf * fc from d
  for (int t = f; t < 16*NB; t += 128){
    int ee = t / NB, k = t % NB;
    float d = dL[ee];
    float c = CUT * (float)k / (float)(NB - 1);
    float tt = (d - c) * ((float)NB / CUT);     // width = 0.25
    float fc = (d < CUT) ? 0.5f*(cosf((float)M_PI * d * (1.0f/CUT)) + 1.0f) : 0.0f;
    rbfL[ee][k] = expf(-tt*tt) * fc;
  }
  __syncthreads();

  float acc[16];
  // me = rbf @ me_W
  #pragma unroll
  for (int ee = 0; ee < 16; ee++) acc[ee] = 0.f;
  #pragma unroll
  for (int k = 0; k < NB; k++){
    float w = meW[k*NF + f];
    #pragma unroll
    for (int ee = 0; ee < 16; ee++) acc[ee] += rbfL[ee][k] * w;
  }
  // msg = me * h[i] * h[j]; atom[i] += msg
  #pragma unroll
  for (int ee = 0; ee < 16; ee++){
    int ii = iiL[ee];
    float m = acc[ee] * h[ii*NF + f] * h[jjL[ee]*NF + f];
    atomicAdd(&atom[ii*NF + f], m);
    msg_lds[ee][f] = m;
  }
  __syncthreads();

  // t1 = silu(msg @ w11)
  #pragma unroll
  for (int ee = 0; ee < 16; ee++) acc[ee] = 0.f;
  #pragma unroll 4
  for (int k = 0; k < NF; k++){
    float w = w11[k*NF + f];
    #pragma unroll
    for (int ee = 0; ee < 16; ee++) acc[ee] += msg_lds[ee][k] * w;
  }
  #pragma unroll
  for (int ee = 0; ee < 16; ee++){ float v = acc[ee]; t_lds[ee][f] = v/(1.f+expf(-v)); }
  __syncthreads();

  // g1 = t1 @ w12
  float g1[16];
  #pragma unroll
  for (int ee = 0; ee < 16; ee++) g1[ee] = 0.f;
  #pragma unroll 4
  for (int k = 0; k < NF; k++){
    float w = w12[k*NF + f];
    #pragma unroll
    for (int ee = 0; ee < 16; ee++) g1[ee] += t_lds[ee][k] * w;
  }
  __syncthreads();

  // t2 = silu(msg @ w21)
  #pragma unroll
  for (int ee = 0; ee < 16; ee++) acc[ee] = 0.f;
  #pragma unroll 4
  for (int k = 0; k < NF; k++){
    float w = w21[k*NF + f];
    #pragma unroll
    for (int ee = 0; ee < 16; ee++) acc[ee] += msg_lds[ee][k] * w;
  }
  #pragma unroll
  for (int ee = 0; ee < 16; ee++){ float v = acc[ee]; t_lds[ee][f] = v/(1.f+expf(-v)); }
  __syncthreads();

  // g2 = t2 @ w22
  float g2[16];
  #pragma unroll
  for (int ee = 0; ee < 16; ee++) g2[ee] = 0.f;
  #pragma unroll 4
  for (int k = 0; k < NF; k++){
    float w = w22[k*NF + f];
    #pragma unroll
    for (int ee = 0; ee < 16; ee++) g2[ee] += t_lds[ee][k] * w;
  }

  // fdelta[i] += g1*dir + g2*force_old[j]
  #pragma unroll
  for (int ee = 0; ee < 16; ee++){
    int ii = iiL[ee], jj = jjL[ee];
    #pragma unroll
    for (int d = 0; d < 3; d++){
      float val = g1[ee]*dirL[ee][d] + g2[ee]*force[jj*(3*NF) + d*NF + f];
      atomicAdd(&fdelta[ii*(3*NF) + d*NF + f], val);
    }
  }
}

// ---------------- node update ----------------
__global__ __launch_bounds__(128) void k_node_update(
    float* __restrict__ force, const float* __restrict__ fdelta,
    const float* __restrict__ euW, float* __restrict__ atom){
  __shared__ float fl[8][3][NF];
  int f = threadIdx.x;
  int n0 = blockIdx.x * 8;
  #pragma unroll
  for (int nn = 0; nn < 8; nn++){
    int n = n0 + nn;
    #pragma unroll
    for (int d = 0; d < 3; d++){
      if (n < NN){
        int idx = n*(3*NF) + d*NF + f;
        float v = force[idx] + fdelta[idx];
        force[idx] = v;
        fl[nn][d][f] = v;
      } else fl[nn][d][f] = 0.f;
    }
  }
  __syncthreads();
  float acc[8][3];
  #pragma unroll
  for (int nn = 0; nn < 8; nn++)
    #pragma unroll
    for (int d = 0; d < 3; d++) acc[nn][d] = 0.f;
  #pragma unroll 4
  for (int k = 0; k < NF; k++){
    float w = euW[k*NF + f];
    #pragma unroll
    for (int nn = 0; nn < 8; nn++)
      #pragma unroll
      for (int d = 0; d < 3; d++) acc[nn][d] += fl[nn][d][k] * w;
  }
  #pragma unroll
  for (int nn = 0; nn < 8; nn++){
    int n = n0 + nn;
    if (n >= NN) continue;
    float s = 0.f;
    #pragma unroll
    for (int d = 0; d < 3; d++) s += fl[nn][d][f] * acc[nn][d];
    atom[n*NF + f] += s;
  }
}

// ---------------- write out: atom then force, dtype per flag ----------------
__global__ __launch_bounds__(256) void k_writeout(const float* __restrict__ atom,
                                                  const float* __restrict__ force,
                                                  void* __restrict__ out,
                                                  const int* __restrict__ flag){
  int idx = blockIdx.x * 256 + threadIdx.x;
  const int na = NN * NF;
  const int tot = na + NN * 3 * NF;
  if (idx >= tot) return;
  float v = (idx < na) ? atom[idx] : force[idx - na];
  if (*flag) ((__hip_bfloat16*)out)[idx] = __float2bfloat16(v);
  else       ((float*)out)[idx] = v;
}

extern "C" void kernel_launch(void* const* d_in, const int* in_sizes, int n_in,
                              void* d_out, int out_size, void* d_ws, size_t ws_size,
                              hipStream_t stream){
  const int* z    = (const int*)d_in[0];
  const void* pos = d_in[1];
  // d_in[2] cell, d_in[3] batch: numerically dead (sym == I)
  const int* ei   = (const int*)d_in[4];
  const void* emb   = d_in[5];
  const void* mnpW1 = d_in[6];
  const void* mnpb1 = d_in[7];
  const void* mnpW2 = d_in[8];
  const void* mnpb2 = d_in[9];
  const void* meW   = d_in[10];
  const void* em1W1 = d_in[11];
  const void* em1W2 = d_in[12];
  const void* em2W1 = d_in[13];
  const void* em2W2 = d_in[14];
  const void* euW   = d_in[15];

  float* base  = (float*)d_ws;
  int*   flag  = (int*)d_ws;            // 4 floats reserved
  float* atom   = base + 4;             // 1,280,000
  float* force  = atom  + NN*NF;        // 3,840,000
  float* fdelta = force + NN*3*NF;      // 3,840,000
  float* h1     = fdelta+ NN*3*NF;      // 1,280,000
  float* h      = h1    + NN*NF;        // 1,280,000
  float* dvals  = h     + NN*NF;        //   160,000
  float* dirv   = dvals + NE;           //   480,000
  float* wbuf   = dirv  + 3*NE;         // fp32 copies of float inputs
  float* posf   = wbuf;                 //  30,000
  float* embf   = posf  + NN*3;         //  15,232
  float* mnpW1f = embf  + 119*NF;       //  49,152
  float* mnpb1f = mnpW1f+ 3*NF*NF;      //     384
  float* mnpW2f = mnpb1f+ 3*NF;         //  49,152
  float* mnpb2f = mnpW2f+ 3*NF*NF;      //     384
  float* meWf   = mnpb2f+ 3*NF;         //   7,680
  float* em1W1f = meWf  + 3*NB*NF;      //  49,152
  float* em1W2f = em1W1f+ 3*NF*NF;
  float* em2W1f = em1W2f+ 3*NF*NF;
  float* em2W2f = em2W1f+ 3*NF*NF;
  float* euWf   = em2W2f+ 3*NF*NF;

  k_detect<<<1, 256, 0, stream>>>(meW, 3*NB*NF, flag);

  #define CVT(src, dst, n) k_cvt<<<((n)+255)/256, 256, 0, stream>>>(src, dst, n, flag)
  CVT(pos,   posf,   NN*3);
  CVT(emb,   embf,   119*NF);
  CVT(mnpW1, mnpW1f, 3*NF*NF);
  CVT(mnpb1, mnpb1f, 3*NF);
  CVT(mnpW2, mnpW2f, 3*NF*NF);
  CVT(mnpb2, mnpb2f, 3*NF);
  CVT(meW,   meWf,   3*NB*NF);
  CVT(em1W1, em1W1f, 3*NF*NF);
  CVT(em1W2, em1W2f, 3*NF*NF);
  CVT(em2W1, em2W1f, 3*NF*NF);
  CVT(em2W2, em2W2f, 3*NF*NF);
  CVT(euW,   euWf,   3*NF*NF);
  #undef CVT

  hipMemsetAsync(force, 0, (size_t)NN*3*NF*sizeof(float), stream);
  k_init_atom<<<(NN*NF+255)/256, 256, 0, stream>>>(z, embf, atom);
  k_edge_embed<<<(NE+255)/256, 256, 0, stream>>>(ei, posf, dvals, dirv);

  for (int l = 0; l < 3; l++){
    k_node_mlp<<<(NN+15)/16, 128, 0, stream>>>(atom, mnpW1f + (size_t)l*NF*NF, mnpb1f + (size_t)l*NF, h1, 1);
    k_node_mlp<<<(NN+15)/16, 128, 0, stream>>>(h1,   mnpW2f + (size_t)l*NF*NF, mnpb2f + (size_t)l*NF, h,  0);
    hipMemsetAsync(fdelta, 0, (size_t)NN*3*NF*sizeof(float), stream);
    k_edge<<<NE/16, 128, 0, stream>>>(ei, dvals, dirv, h,
        meWf + (size_t)l*NB*NF,
        em1W1f + (size_t)l*NF*NF, em1W2f + (size_t)l*NF*NF,
        em2W1f + (size_t)l*NF*NF, em2W2f + (size_t)l*NF*NF,
        atom, force, fdelta);
    k_node_update<<<(NN+7)/8, 128, 0, stream>>>(force, fdelta, euWf + (size_t)l*NF*NF, atom);
  }

  k_writeout<<<(NN*NF + NN*3*NF + 255)/256, 256, 0, stream>>>(atom, force, d_out, flag);
}

// Round 3
// 2111.086 us; speedup vs baseline: 1.2623x; 1.2623x over previous
//
#include <hip/hip_runtime.h>
#include <hip/hip_bf16.h>
#include <math.h>

#define NN 10000
#define NE 160000
#define NF 128
#define NB 20
#define CUT 5.0f

typedef __attribute__((ext_vector_type(8))) short short8;
typedef __attribute__((ext_vector_type(4))) float floatx4;

__device__ __forceinline__ unsigned short f2b(float x){
  union { __hip_bfloat16 b; unsigned short u; } cv;
  cv.b = __float2bfloat16(x);
  return cv.u;
}

// ---------------- dtype detector: 1=bf16, 0=fp32 ----------------
__global__ __launch_bounds__(256) void k_detect(const void* __restrict__ w, int nelem,
                                                int* __restrict__ flag){
  __shared__ int cnt;
  if (threadIdx.x == 0) cnt = 0;
  __syncthreads();
  const unsigned short* hw = (const unsigned short*)w;
  int local = 0;
  for (int k = threadIdx.x; k < nelem; k += 256){
    unsigned short h = hw[k];
    int e = (h >> 7) & 0xFF;
    if ((h & 0x7FFF) == 0 || (e >= 103 && e <= 130)) local++;
  }
  atomicAdd(&cnt, local);
  __syncthreads();
  if (threadIdx.x == 0) *flag = (cnt >= (nelem * 9) / 10) ? 1 : 0;
}

// ---------------- generic convert-to-fp32 ----------------
__global__ __launch_bounds__(256) void k_cvt(const void* __restrict__ src, float* __restrict__ dst,
                                             int n, const int* __restrict__ flag){
  int i = blockIdx.x * 256 + threadIdx.x;
  if (i >= n) return;
  int isb = *flag;
  dst[i] = isb ? __bfloat162float(((const __hip_bfloat16*)src)[i])
               : ((const float*)src)[i];
}

// ---------------- weight swizzle to MFMA B-fragment layout ----------------
// out[((tk*8+tn)*64+lane)*8+j] = bf16( W[k*128+n] ), k=tk*32+(lane>>4)*8+j, n=tn*16+(lane&15)
__global__ __launch_bounds__(256) void k_swz128(const float* __restrict__ W, unsigned short* __restrict__ out){
  int idx = blockIdx.x*256 + threadIdx.x;     // 3*16384 (3 layers)
  if (idx >= 3*16384) return;
  int l = idx >> 14, rem = idx & 16383;
  int j = rem & 7, lane = (rem >> 3) & 63, tn = (rem >> 9) & 7, tk = rem >> 12;
  int k = tk*32 + ((lane >> 4) & 3)*8 + j, n = tn*16 + (lane & 15);
  out[idx] = f2b(W[l*16384 + k*NF + n]);
}
// me_W: 20x128 zero-padded to K=32 (single K-block)
__global__ __launch_bounds__(256) void k_swzme(const float* __restrict__ W, unsigned short* __restrict__ out){
  int idx = blockIdx.x*256 + threadIdx.x;     // 3*4096
  if (idx >= 3*4096) return;
  int l = idx >> 12, rem = idx & 4095;
  int j = rem & 7, lane = (rem >> 3) & 63, tn = rem >> 9;
  int k = ((lane >> 4) & 3)*8 + j, n = tn*16 + (lane & 15);
  out[idx] = (k < NB) ? f2b(W[l*NB*NF + k*NF + n]) : (unsigned short)0;
}

// ---------------- init: atom = node_emb[z] ----------------
__global__ __launch_bounds__(256) void k_init_atom(const int* __restrict__ z,
                                                   const float* __restrict__ emb,
                                                   float* __restrict__ atom){
  int idx = blockIdx.x * 256 + threadIdx.x;
  if (idx >= NN * NF) return;
  int n = idx >> 7, f = idx & (NF - 1);
  atom[idx] = emb[z[n] * NF + f];
}

// ---------------- edge embedding: d (E,), dir (E,3) ----------------
__global__ __launch_bounds__(256) void k_edge_embed(const int* __restrict__ ei,
                                                    const float* __restrict__ pos,
                                                    float* __restrict__ dvals,
                                                    float* __restrict__ dirv){
  int e = blockIdx.x * 256 + threadIdx.x;
  if (e >= NE) return;
  int i = ei[e], j = ei[NE + e];
  float dx = pos[j*3+0] - pos[i*3+0];
  float dy = pos[j*3+1] - pos[i*3+1];
  float dz = pos[j*3+2] - pos[i*3+2];
  float d = sqrtf(dx*dx + dy*dy + dz*dz + 1e-12f);
  float inv = 1.0f / d;
  dvals[e] = d;
  dirv[e*3+0] = dx*inv; dirv[e*3+1] = dy*inv; dirv[e*3+2] = dz*inv;
}

// ---------------- node MLP (unchanged) ----------------
__global__ __launch_bounds__(128) void k_node_mlp(const float* __restrict__ in,
                                                  const float* __restrict__ W,
                                                  const float* __restrict__ b,
                                                  float* __restrict__ out, int apply_silu){
  __shared__ float a_lds[16][NF];
  int f = threadIdx.x;
  int n0 = blockIdx.x * 16;
  #pragma unroll
  for (int nn = 0; nn < 16; nn++){
    int n = n0 + nn;
    a_lds[nn][f] = (n < NN) ? in[n*NF + f] : 0.f;
  }
  __syncthreads();
  float acc[16];
  #pragma unroll
  for (int nn = 0; nn < 16; nn++) acc[nn] = 0.f;
  #pragma unroll 4
  for (int k = 0; k < NF; k++){
    float w = W[k*NF + f];
    #pragma unroll
    for (int nn = 0; nn < 16; nn++) acc[nn] += a_lds[nn][k] * w;
  }
  float bias = b[f];
  #pragma unroll
  for (int nn = 0; nn < 16; nn++){
    int n = n0 + nn;
    if (n < NN){
      float v = acc[nn] + bias;
      if (apply_silu) v = v / (1.f + expf(-v));
      out[n*NF + f] = v;
    }
  }
}

// ---------------- MFMA edge kernel: 1 wave, 16 edges/block ----------------
__global__ __launch_bounds__(64) void k_edge_mfma(
    const int* __restrict__ ei, const float* __restrict__ dvals, const float* __restrict__ dirv,
    const float* __restrict__ h,
    const unsigned short* __restrict__ mesw,
    const unsigned short* __restrict__ w11sw, const unsigned short* __restrict__ w12sw,
    const unsigned short* __restrict__ w21sw, const unsigned short* __restrict__ w22sw,
    float* __restrict__ atom, const float* __restrict__ force, float* __restrict__ fdelta)
{
  __shared__ __align__(16) unsigned short msgA[4][64][8];  // A-frags of msg (K=128)
  __shared__ __align__(16) unsigned short tA[4][64][8];    // A-frags of t1/t2 (reused)

  const int lane = threadIdx.x;
  const int q    = lane >> 4;     // 0..3
  const int ln   = lane & 15;
  const int e0   = blockIdx.x * 16;   // grid = NE/16 exactly

  // C-layout row metadata: rows m_r = q*4+r
  int iiR[4], jjR[4];
  float dirR[4][3];
  #pragma unroll
  for (int r = 0; r < 4; r++){
    int e = e0 + q*4 + r;
    iiR[r] = ei[e]; jjR[r] = ei[NE + e];
    dirR[r][0] = dirv[e*3+0]; dirR[r][1] = dirv[e*3+1]; dirR[r][2] = dirv[e*3+2];
  }

  // A-fragment of rbf: lane holds edge m=ln, k = q*8+j (K padded 20->32)
  float dA  = dvals[e0 + ln];
  float fcA = (dA < CUT) ? 0.5f*(cosf((float)M_PI*dA*(1.0f/CUT)) + 1.0f) : 0.0f;
  short8 a_rbf;
  #pragma unroll
  for (int j = 0; j < 8; j++){
    int k = q*8 + j;
    float v = 0.f;
    if (k < NB){
      float t = (dA - CUT*(float)k/(float)(NB-1)) * ((float)NB/CUT);
      v = expf(-t*t) * fcA;
    }
    a_rbf[j] = (short)f2b(v);
  }

  // me = rbf @ meW (MFMA), msg = me*h[i]*h[j]; atom[i] += msg; msg -> LDS A-frags
  #pragma unroll
  for (int tn = 0; tn < 8; tn++){
    short8 b = *(const short8*)(mesw + (size_t)(tn*64 + lane)*8);
    floatx4 c = {0.f,0.f,0.f,0.f};
    c = __builtin_amdgcn_mfma_f32_16x16x32_bf16(a_rbf, b, c, 0, 0, 0);
    int n = tn*16 + ln;
    #pragma unroll
    for (int r = 0; r < 4; r++){
      int m = q*4 + r;
      float mv = c[r] * h[iiR[r]*NF + n] * h[jjR[r]*NF + n];
      atomicAdd(&atom[iiR[r]*NF + n], mv);
      msgA[n >> 5][(((n >> 3) & 3) << 4) | m][n & 7] = f2b(mv);
    }
  }
  __syncthreads();

  // t1 = silu(msg @ w11) -> tA
  #pragma unroll
  for (int tn = 0; tn < 8; tn++){
    floatx4 c = {0.f,0.f,0.f,0.f};
    #pragma unroll
    for (int tk = 0; tk < 4; tk++){
      short8 a = *(const short8*)msgA[tk][lane];
      short8 b = *(const short8*)(w11sw + (size_t)((tk*8 + tn)*64 + lane)*8);
      c = __builtin_amdgcn_mfma_f32_16x16x32_bf16(a, b, c, 0, 0, 0);
    }
    int n = tn*16 + ln;
    #pragma unroll
    for (int r = 0; r < 4; r++){
      float v = c[r]; v = v / (1.f + expf(-v));
      tA[n >> 5][(((n >> 3) & 3) << 4) | (q*4 + r)][n & 7] = f2b(v);
    }
  }
  __syncthreads();

  // g1 = t1 @ w12 (keep in registers)
  float g1[8][4];
  #pragma unroll
  for (int tn = 0; tn < 8; tn++){
    floatx4 c = {0.f,0.f,0.f,0.f};
    #pragma unroll
    for (int tk = 0; tk < 4; tk++){
      short8 a = *(const short8*)tA[tk][lane];
      short8 b = *(const short8*)(w12sw + (size_t)((tk*8 + tn)*64 + lane)*8);
      c = __builtin_amdgcn_mfma_f32_16x16x32_bf16(a, b, c, 0, 0, 0);
    }
    #pragma unroll
    for (int r = 0; r < 4; r++) g1[tn][r] = c[r];
  }
  __syncthreads();   // before overwriting tA

  // t2 = silu(msg @ w21) -> tA
  #pragma unroll
  for (int tn = 0; tn < 8; tn++){
    floatx4 c = {0.f,0.f,0.f,0.f};
    #pragma unroll
    for (int tk = 0; tk < 4; tk++){
      short8 a = *(const short8*)msgA[tk][lane];
      short8 b = *(const short8*)(w21sw + (size_t)((tk*8 + tn)*64 + lane)*8);
      c = __builtin_amdgcn_mfma_f32_16x16x32_bf16(a, b, c, 0, 0, 0);
    }
    int n = tn*16 + ln;
    #pragma unroll
    for (int r = 0; r < 4; r++){
      float v = c[r]; v = v / (1.f + expf(-v));
      tA[n >> 5][(((n >> 3) & 3) << 4) | (q*4 + r)][n & 7] = f2b(v);
    }
  }
  __syncthreads();

  // g2 = t2 @ w22, fused scatter: fdelta[i] += g1*dir + g2*force_old[j]
  #pragma unroll
  for (int tn = 0; tn < 8; tn++){
    floatx4 c = {0.f,0.f,0.f,0.f};
    #pragma unroll
    for (int tk = 0; tk < 4; tk++){
      short8 a = *(const short8*)tA[tk][lane];
      short8 b = *(const short8*)(w22sw + (size_t)((tk*8 + tn)*64 + lane)*8);
      c = __builtin_amdgcn_mfma_f32_16x16x32_bf16(a, b, c, 0, 0, 0);
    }
    int n = tn*16 + ln;
    #pragma unroll
    for (int r = 0; r < 4; r++){
      float fg1 = g1[tn][r], fg2 = c[r];
      int ii = iiR[r], jj = jjR[r];
      #pragma unroll
      for (int d = 0; d < 3; d++){
        float val = fg1*dirR[r][d] + fg2*force[jj*(3*NF) + d*NF + n];
        atomicAdd(&fdelta[ii*(3*NF) + d*NF + n], val);
      }
    }
  }
}

// ---------------- node update (unchanged) ----------------
__global__ __launch_bounds__(128) void k_node_update(
    float* __restrict__ force, const float* __restrict__ fdelta,
    const float* __restrict__ euW, float* __restrict__ atom){
  __shared__ float fl[8][3][NF];
  int f = threadIdx.x;
  int n0 = blockIdx.x * 8;
  #pragma unroll
  for (int nn = 0; nn < 8; nn++){
    int n = n0 + nn;
    #pragma unroll
    for (int d = 0; d < 3; d++){
      if (n < NN){
        int idx = n*(3*NF) + d*NF + f;
        float v = force[idx] + fdelta[idx];
        force[idx] = v;
        fl[nn][d][f] = v;
      } else fl[nn][d][f] = 0.f;
    }
  }
  __syncthreads();
  float acc[8][3];
  #pragma unroll
  for (int nn = 0; nn < 8; nn++)
    #pragma unroll
    for (int d = 0; d < 3; d++) acc[nn][d] = 0.f;
  #pragma unroll 4
  for (int k = 0; k < NF; k++){
    float w = euW[k*NF + f];
    #pragma unroll
    for (int nn = 0; nn < 8; nn++)
      #pragma unroll
      for (int d = 0; d < 3; d++) acc[nn][d] += fl[nn][d][k] * w;
  }
  #pragma unroll
  for (int nn = 0; nn < 8; nn++){
    int n = n0 + nn;
    if (n >= NN) continue;
    float s = 0.f;
    #pragma unroll
    for (int d = 0; d < 3; d++) s += fl[nn][d][f] * acc[nn][d];
    atom[n*NF + f] += s;
  }
}

// ---------------- write out ----------------
__global__ __launch_bounds__(256) void k_writeout(const float* __restrict__ atom,
                                                  const float* __restrict__ force,
                                                  void* __restrict__ out,
                                                  const int* __restrict__ flag){
  int idx = blockIdx.x * 256 + threadIdx.x;
  const int na = NN * NF;
  const int tot = na + NN * 3 * NF;
  if (idx >= tot) return;
  float v = (idx < na) ? atom[idx] : force[idx - na];
  if (*flag) ((__hip_bfloat16*)out)[idx] = __float2bfloat16(v);
  else       ((float*)out)[idx] = v;
}

extern "C" void kernel_launch(void* const* d_in, const int* in_sizes, int n_in,
                              void* d_out, int out_size, void* d_ws, size_t ws_size,
                              hipStream_t stream){
  const int* z    = (const int*)d_in[0];
  const void* pos = d_in[1];
  // d_in[2] cell, d_in[3] batch: numerically dead (sym == I)
  const int* ei   = (const int*)d_in[4];
  const void* emb   = d_in[5];
  const void* mnpW1 = d_in[6];
  const void* mnpb1 = d_in[7];
  const void* mnpW2 = d_in[8];
  const void* mnpb2 = d_in[9];
  const void* meW   = d_in[10];
  const void* em1W1 = d_in[11];
  const void* em1W2 = d_in[12];
  const void* em2W1 = d_in[13];
  const void* em2W2 = d_in[14];
  const void* euW   = d_in[15];

  float* base  = (float*)d_ws;
  int*   flag  = (int*)d_ws;            // 4 floats reserved
  float* atom   = base + 4;             // 1,280,000
  float* force  = atom  + NN*NF;        // 3,840,000
  float* fdelta = force + NN*3*NF;      // 3,840,000
  float* h1     = fdelta+ NN*3*NF;      // 1,280,000
  float* h      = h1    + NN*NF;        // 1,280,000
  float* dvals  = h     + NN*NF;        //   160,000
  float* dirv   = dvals + NE;           //   480,000
  float* wbuf   = dirv  + 3*NE;
  float* posf   = wbuf;                 //  30,000
  float* embf   = posf  + NN*3;         //  15,232
  float* mnpW1f = embf  + 119*NF;
  float* mnpb1f = mnpW1f+ 3*NF*NF;
  float* mnpW2f = mnpb1f+ 3*NF;
  float* mnpb2f = mnpW2f+ 3*NF*NF;
  float* meWf   = mnpb2f+ 3*NF;
  float* em1W1f = meWf  + 3*NB*NF;
  float* em1W2f = em1W1f+ 3*NF*NF;
  float* em2W1f = em1W2f+ 3*NF*NF;
  float* em2W2f = em2W1f+ 3*NF*NF;
  float* euWf   = em2W2f+ 3*NF*NF;
  // bf16 B-fragment-swizzled weights
  unsigned short* mesw  = (unsigned short*)(euWf + 3*NF*NF);
  unsigned short* w11sw = mesw  + 3*4096;
  unsigned short* w12sw = w11sw + 3*16384;
  unsigned short* w21sw = w12sw + 3*16384;
  unsigned short* w22sw = w21sw + 3*16384;

  k_detect<<<1, 256, 0, stream>>>(meW, 3*NB*NF, flag);

  #define CVT(src, dst, n) k_cvt<<<((n)+255)/256, 256, 0, stream>>>(src, dst, n, flag)
  CVT(pos,   posf,   NN*3);
  CVT(emb,   embf,   119*NF);
  CVT(mnpW1, mnpW1f, 3*NF*NF);
  CVT(mnpb1, mnpb1f, 3*NF);
  CVT(mnpW2, mnpW2f, 3*NF*NF);
  CVT(mnpb2, mnpb2f, 3*NF);
  CVT(meW,   meWf,   3*NB*NF);
  CVT(em1W1, em1W1f, 3*NF*NF);
  CVT(em1W2, em1W2f, 3*NF*NF);
  CVT(em2W1, em2W1f, 3*NF*NF);
  CVT(em2W2, em2W2f, 3*NF*NF);
  CVT(euW,   euWf,   3*NF*NF);
  #undef CVT

  k_swzme <<<(3*4096 +255)/256, 256, 0, stream>>>(meWf,   mesw);
  k_swz128<<<(3*16384+255)/256, 256, 0, stream>>>(em1W1f, w11sw);
  k_swz128<<<(3*16384+255)/256, 256, 0, stream>>>(em1W2f, w12sw);
  k_swz128<<<(3*16384+255)/256, 256, 0, stream>>>(em2W1f, w21sw);
  k_swz128<<<(3*16384+255)/256, 256, 0, stream>>>(em2W2f, w22sw);

  hipMemsetAsync(force, 0, (size_t)NN*3*NF*sizeof(float), stream);
  k_init_atom<<<(NN*NF+255)/256, 256, 0, stream>>>(z, embf, atom);
  k_edge_embed<<<(NE+255)/256, 256, 0, stream>>>(ei, posf, dvals, dirv);

  for (int l = 0; l < 3; l++){
    k_node_mlp<<<(NN+15)/16, 128, 0, stream>>>(atom, mnpW1f + (size_t)l*NF*NF, mnpb1f + (size_t)l*NF, h1, 1);
    k_node_mlp<<<(NN+15)/16, 128, 0, stream>>>(h1,   mnpW2f + (size_t)l*NF*NF, mnpb2f + (size_t)l*NF, h,  0);
    hipMemsetAsync(fdelta, 0, (size_t)NN*3*NF*sizeof(float), stream);
    k_edge_mfma<<<NE/16, 64, 0, stream>>>(ei, dvals, dirv, h,
        mesw  + (size_t)l*4096,
        w11sw + (size_t)l*16384, w12sw + (size_t)l*16384,
        w21sw + (size_t)l*16384, w22sw + (size_t)l*16384,
        atom, force, fdelta);
    k_node_update<<<(NN+7)/8, 128, 0, stream>>>(force, fdelta, euWf + (size_t)l*NF*NF, atom);
  }

  k_writeout<<<(NN*NF + NN*3*NF + 255)/256, 256, 0, stream>>>(atom, force, d_out, flag);
}

// Round 4
// 1252.529 us; speedup vs baseline: 2.1276x; 1.6855x over previous
//
#include <hip/hip_runtime.h>
#include <hip/hip_bf16.h>
#include <math.h>

#define NN 10000
#define NE 160000
#define NF 128
#define NB 20
#define CUT 5.0f
#define TP 132   // padded tile stride (floats): 2-way LDS aliasing only

typedef __attribute__((ext_vector_type(8))) short short8;
typedef __attribute__((ext_vector_type(4))) float floatx4;

__device__ __forceinline__ unsigned short f2b(float x){
  union { __hip_bfloat16 b; unsigned short u; } cv;
  cv.b = __float2bfloat16(x);
  return cv.u;
}

// ---------------- dtype detector: 1=bf16, 0=fp32 ----------------
__global__ __launch_bounds__(256) void k_detect(const void* __restrict__ w, int nelem,
                                                int* __restrict__ flag){
  __shared__ int cnt;
  if (threadIdx.x == 0) cnt = 0;
  __syncthreads();
  const unsigned short* hw = (const unsigned short*)w;
  int local = 0;
  for (int k = threadIdx.x; k < nelem; k += 256){
    unsigned short h = hw[k];
    int e = (h >> 7) & 0xFF;
    if ((h & 0x7FFF) == 0 || (e >= 103 && e <= 130)) local++;
  }
  atomicAdd(&cnt, local);
  __syncthreads();
  if (threadIdx.x == 0) *flag = (cnt >= (nelem * 9) / 10) ? 1 : 0;
}

// ---------------- generic convert-to-fp32 ----------------
__global__ __launch_bounds__(256) void k_cvt(const void* __restrict__ src, float* __restrict__ dst,
                                             int n, const int* __restrict__ flag){
  int i = blockIdx.x * 256 + threadIdx.x;
  if (i >= n) return;
  int isb = *flag;
  dst[i] = isb ? __bfloat162float(((const __hip_bfloat16*)src)[i])
               : ((const float*)src)[i];
}

// ---------------- counting sort of edges by destination i ----------------
__global__ __launch_bounds__(256) void k_hist(const int* __restrict__ ei, int* __restrict__ count){
  int e = blockIdx.x*256 + threadIdx.x;
  if (e < NE) atomicAdd(&count[ei[e]], 1);
}
// single-block exclusive scan over NN counts -> rowptr[NN+1]; cursor = rowptr copy
__global__ __launch_bounds__(256) void k_scan(const int* __restrict__ count,
                                              int* __restrict__ rowptr, int* __restrict__ cursor){
  __shared__ int part[256];
  const int CH = (NN + 255) / 256;  // 40
  int t = threadIdx.x;
  int base = t * CH;
  int s = 0;
  for (int k = 0; k < CH; k++){ int i = base + k; if (i < NN) s += count[i]; }
  part[t] = s;
  __syncthreads();
  for (int off = 1; off < 256; off <<= 1){
    int v = (t >= off) ? part[t - off] : 0;
    __syncthreads();
    part[t] += v;
    __syncthreads();
  }
  int run = (t == 0) ? 0 : part[t - 1];
  for (int k = 0; k < CH; k++){
    int i = base + k;
    if (i < NN){ rowptr[i] = run; cursor[i] = run; run += count[i]; }
  }
  if (t == 255) rowptr[NN] = run;
}
__global__ __launch_bounds__(256) void k_scatter(const int* __restrict__ ei,
                                                 int* __restrict__ cursor, int* __restrict__ perm){
  int e = blockIdx.x*256 + threadIdx.x;
  if (e >= NE) return;
  int pos = atomicAdd(&cursor[ei[e]], 1);
  perm[pos] = e;
}

// ---------------- weight swizzle to MFMA B-fragment layout ----------------
__global__ __launch_bounds__(256) void k_swz128(const float* __restrict__ W, unsigned short* __restrict__ out){
  int idx = blockIdx.x*256 + threadIdx.x;     // 3*16384
  if (idx >= 3*16384) return;
  int l = idx >> 14, rem = idx & 16383;
  int j = rem & 7, lane = (rem >> 3) & 63, tn = (rem >> 9) & 7, tk = rem >> 12;
  int k = tk*32 + ((lane >> 4) & 3)*8 + j, n = tn*16 + (lane & 15);
  out[idx] = f2b(W[l*16384 + k*NF + n]);
}
__global__ __launch_bounds__(256) void k_swzme(const float* __restrict__ W, unsigned short* __restrict__ out){
  int idx = blockIdx.x*256 + threadIdx.x;     // 3*4096
  if (idx >= 3*4096) return;
  int l = idx >> 12, rem = idx & 4095;
  int j = rem & 7, lane = (rem >> 3) & 63, tn = rem >> 9;
  int k = ((lane >> 4) & 3)*8 + j, n = tn*16 + (lane & 15);
  out[idx] = (k < NB) ? f2b(W[l*NB*NF + k*NF + n]) : (unsigned short)0;
}

// ---------------- init / edge embedding ----------------
__global__ __launch_bounds__(256) void k_init_atom(const int* __restrict__ z,
                                                   const float* __restrict__ emb,
                                                   float* __restrict__ atom){
  int idx = blockIdx.x * 256 + threadIdx.x;
  if (idx >= NN * NF) return;
  int n = idx >> 7, f = idx & (NF - 1);
  atom[idx] = emb[z[n] * NF + f];
}
__global__ __launch_bounds__(256) void k_edge_embed(const int* __restrict__ ei,
                                                    const float* __restrict__ pos,
                                                    float* __restrict__ dvals,
                                                    float* __restrict__ dirv){
  int e = blockIdx.x * 256 + threadIdx.x;
  if (e >= NE) return;
  int i = ei[e], j = ei[NE + e];
  float dx = pos[j*3+0] - pos[i*3+0];
  float dy = pos[j*3+1] - pos[i*3+1];
  float dz = pos[j*3+2] - pos[i*3+2];
  float d = sqrtf(dx*dx + dy*dy + dz*dz + 1e-12f);
  float inv = 1.0f / d;
  dvals[e] = d;
  dirv[e*3+0] = dx*inv; dirv[e*3+1] = dy*inv; dirv[e*3+2] = dz*inv;
}

// ---------------- node MLP ----------------
__global__ __launch_bounds__(128) void k_node_mlp(const float* __restrict__ in,
                                                  const float* __restrict__ W,
                                                  const float* __restrict__ b,
                                                  float* __restrict__ out, int apply_silu){
  __shared__ float a_lds[16][NF];
  int f = threadIdx.x;
  int n0 = blockIdx.x * 16;
  #pragma unroll
  for (int nn = 0; nn < 16; nn++){
    int n = n0 + nn;
    a_lds[nn][f] = (n < NN) ? in[n*NF + f] : 0.f;
  }
  __syncthreads();
  float acc[16];
  #pragma unroll
  for (int nn = 0; nn < 16; nn++) acc[nn] = 0.f;
  #pragma unroll 4
  for (int k = 0; k < NF; k++){
    float w = W[k*NF + f];
    #pragma unroll
    for (int nn = 0; nn < 16; nn++) acc[nn] += a_lds[nn][k] * w;
  }
  float bias = b[f];
  #pragma unroll
  for (int nn = 0; nn < 16; nn++){
    int n = n0 + nn;
    if (n < NN){
      float v = acc[nn] + bias;
      if (apply_silu) v = v / (1.f + expf(-v));
      out[n*NF + f] = v;
    }
  }
}

// ---------------- MFMA edge kernel on SORTED edges, LDS-aggregated scatter ----------------
__global__ __launch_bounds__(64) void k_edge_mfma(
    const int* __restrict__ ei, const int* __restrict__ perm,
    const float* __restrict__ dvals, const float* __restrict__ dirv,
    const float* __restrict__ h,
    const unsigned short* __restrict__ mesw,
    const unsigned short* __restrict__ w11sw, const unsigned short* __restrict__ w12sw,
    const unsigned short* __restrict__ w21sw, const unsigned short* __restrict__ w22sw,
    float* __restrict__ atom, const float* __restrict__ force, float* __restrict__ fdelta)
{
  __shared__ __align__(16) unsigned short msgA[4][64][8];  // bf16 A-frags of msg
  __shared__ __align__(16) unsigned short tA[4][64][8];    // bf16 A-frags of t1/t2
  __shared__ float tile[16][TP];                           // fp32 contribution tile
  __shared__ int   iiS[16];

  const int lane = threadIdx.x;
  const int q    = lane >> 4;
  const int ln   = lane & 15;
  const int e0   = blockIdx.x * 16;   // grid = NE/16 exactly

  if (lane < 16) iiS[lane] = ei[perm[e0 + lane]];

  int iiR[4], jjR[4];
  float dirR[4][3];
  #pragma unroll
  for (int r = 0; r < 4; r++){
    int e = perm[e0 + q*4 + r];
    iiR[r] = ei[e]; jjR[r] = ei[NE + e];
    dirR[r][0] = dirv[e*3+0]; dirR[r][1] = dirv[e*3+1]; dirR[r][2] = dirv[e*3+2];
  }

  // A-fragment of rbf: lane holds sorted edge m=ln, k=q*8+j (K padded 20->32)
  int eA = perm[e0 + ln];
  float dA  = dvals[eA];
  float fcA = (dA < CUT) ? 0.5f*(cosf((float)M_PI*dA*(1.0f/CUT)) + 1.0f) : 0.0f;
  short8 a_rbf;
  #pragma unroll
  for (int j = 0; j < 8; j++){
    int k = q*8 + j;
    float v = 0.f;
    if (k < NB){
      float t = (dA - CUT*(float)k/(float)(NB-1)) * ((float)NB/CUT);
      v = expf(-t*t) * fcA;
    }
    a_rbf[j] = (short)f2b(v);
  }

  // me = rbf @ meW; msg = me*h[i]*h[j]; tile <- msg; msgA <- bf16(msg)
  #pragma unroll
  for (int tn = 0; tn < 8; tn++){
    short8 b = *(const short8*)(mesw + (size_t)(tn*64 + lane)*8);
    floatx4 c = {0.f,0.f,0.f,0.f};
    c = __builtin_amdgcn_mfma_f32_16x16x32_bf16(a_rbf, b, c, 0, 0, 0);
    int n = tn*16 + ln;
    #pragma unroll
    for (int r = 0; r < 4; r++){
      int m = q*4 + r;
      float mv = c[r] * h[iiR[r]*NF + n] * h[jjR[r]*NF + n];
      tile[m][n] = mv;
      msgA[n >> 5][(((n >> 3) & 3) << 4) | m][n & 7] = f2b(mv);
    }
  }
  __syncthreads();

  // segment flush: atom[i] += sum of msg rows with destination i
  {
    int seg = 0;
    for (int m = 1; m <= 16; m++){
      if (m == 16 || iiS[m] != iiS[seg]){
        int ii = iiS[seg];
        for (int c = lane; c < NF; c += 64){
          float s = 0.f;
          for (int r = seg; r < m; r++) s += tile[r][c];
          atomicAdd(&atom[ii*NF + c], s);
        }
        seg = m;
      }
    }
  }
  __syncthreads();

  // t1 = silu(msg @ w11) -> tA
  #pragma unroll
  for (int tn = 0; tn < 8; tn++){
    floatx4 c = {0.f,0.f,0.f,0.f};
    #pragma unroll
    for (int tk = 0; tk < 4; tk++){
      short8 a = *(const short8*)msgA[tk][lane];
      short8 b = *(const short8*)(w11sw + (size_t)((tk*8 + tn)*64 + lane)*8);
      c = __builtin_amdgcn_mfma_f32_16x16x32_bf16(a, b, c, 0, 0, 0);
    }
    int n = tn*16 + ln;
    #pragma unroll
    for (int r = 0; r < 4; r++){
      float v = c[r]; v = v / (1.f + expf(-v));
      tA[n >> 5][(((n >> 3) & 3) << 4) | (q*4 + r)][n & 7] = f2b(v);
    }
  }
  __syncthreads();

  // g1 = t1 @ w12
  float g1[8][4];
  #pragma unroll
  for (int tn = 0; tn < 8; tn++){
    floatx4 c = {0.f,0.f,0.f,0.f};
    #pragma unroll
    for (int tk = 0; tk < 4; tk++){
      short8 a = *(const short8*)tA[tk][lane];
      short8 b = *(const short8*)(w12sw + (size_t)((tk*8 + tn)*64 + lane)*8);
      c = __builtin_amdgcn_mfma_f32_16x16x32_bf16(a, b, c, 0, 0, 0);
    }
    #pragma unroll
    for (int r = 0; r < 4; r++) g1[tn][r] = c[r];
  }
  __syncthreads();

  // t2 = silu(msg @ w21) -> tA
  #pragma unroll
  for (int tn = 0; tn < 8; tn++){
    floatx4 c = {0.f,0.f,0.f,0.f};
    #pragma unroll
    for (int tk = 0; tk < 4; tk++){
      short8 a = *(const short8*)msgA[tk][lane];
      short8 b = *(const short8*)(w21sw + (size_t)((tk*8 + tn)*64 + lane)*8);
      c = __builtin_amdgcn_mfma_f32_16x16x32_bf16(a, b, c, 0, 0, 0);
    }
    int n = tn*16 + ln;
    #pragma unroll
    for (int r = 0; r < 4; r++){
      float v = c[r]; v = v / (1.f + expf(-v));
      tA[n >> 5][(((n >> 3) & 3) << 4) | (q*4 + r)][n & 7] = f2b(v);
    }
  }
  __syncthreads();

  // g2 = t2 @ w22
  float g2[8][4];
  #pragma unroll
  for (int tn = 0; tn < 8; tn++){
    floatx4 c = {0.f,0.f,0.f,0.f};
    #pragma unroll
    for (int tk = 0; tk < 4; tk++){
      short8 a = *(const short8*)tA[tk][lane];
      short8 b = *(const short8*)(w22sw + (size_t)((tk*8 + tn)*64 + lane)*8);
      c = __builtin_amdgcn_mfma_f32_16x16x32_bf16(a, b, c, 0, 0, 0);
    }
    #pragma unroll
    for (int r = 0; r < 4; r++) g2[tn][r] = c[r];
  }

  // three d-passes: tile <- g1*dir + g2*force_old[j]; segment flush into fdelta
  for (int d = 0; d < 3; d++){
    __syncthreads();
    #pragma unroll
    for (int tn = 0; tn < 8; tn++){
      int n = tn*16 + ln;
      #pragma unroll
      for (int r = 0; r < 4; r++){
        tile[q*4 + r][n] = g1[tn][r]*dirR[r][d] + g2[tn][r]*force[jjR[r]*(3*NF) + d*NF + n];
      }
    }
    __syncthreads();
    int seg = 0;
    for (int m = 1; m <= 16; m++){
      if (m == 16 || iiS[m] != iiS[seg]){
        int ii = iiS[seg];
        for (int c = lane; c < NF; c += 64){
          float s = 0.f;
          for (int r = seg; r < m; r++) s += tile[r][c];
          atomicAdd(&fdelta[ii*(3*NF) + d*NF + c], s);
        }
        seg = m;
      }
    }
  }
}

// ---------------- node update ----------------
__global__ __launch_bounds__(128) void k_node_update(
    float* __restrict__ force, const float* __restrict__ fdelta,
    const float* __restrict__ euW, float* __restrict__ atom){
  __shared__ float fl[8][3][NF];
  int f = threadIdx.x;
  int n0 = blockIdx.x * 8;
  #pragma unroll
  for (int nn = 0; nn < 8; nn++){
    int n = n0 + nn;
    #pragma unroll
    for (int d = 0; d < 3; d++){
      if (n < NN){
        int idx = n*(3*NF) + d*NF + f;
        float v = force[idx] + fdelta[idx];
        force[idx] = v;
        fl[nn][d][f] = v;
      } else fl[nn][d][f] = 0.f;
    }
  }
  __syncthreads();
  float acc[8][3];
  #pragma unroll
  for (int nn = 0; nn < 8; nn++)
    #pragma unroll
    for (int d = 0; d < 3; d++) acc[nn][d] = 0.f;
  #pragma unroll 4
  for (int k = 0; k < NF; k++){
    float w = euW[k*NF + f];
    #pragma unroll
    for (int nn = 0; nn < 8; nn++)
      #pragma unroll
      for (int d = 0; d < 3; d++) acc[nn][d] += fl[nn][d][k] * w;
  }
  #pragma unroll
  for (int nn = 0; nn < 8; nn++){
    int n = n0 + nn;
    if (n >= NN) continue;
    float s = 0.f;
    #pragma unroll
    for (int d = 0; d < 3; d++) s += fl[nn][d][f] * acc[nn][d];
    atom[n*NF + f] += s;
  }
}

// ---------------- write out ----------------
__global__ __launch_bounds__(256) void k_writeout(const float* __restrict__ atom,
                                                  const float* __restrict__ force,
                                                  void* __restrict__ out,
                                                  const int* __restrict__ flag){
  int idx = blockIdx.x * 256 + threadIdx.x;
  const int na = NN * NF;
  const int tot = na + NN * 3 * NF;
  if (idx >= tot) return;
  float v = (idx < na) ? atom[idx] : force[idx - na];
  if (*flag) ((__hip_bfloat16*)out)[idx] = __float2bfloat16(v);
  else       ((float*)out)[idx] = v;
}

extern "C" void kernel_launch(void* const* d_in, const int* in_sizes, int n_in,
                              void* d_out, int out_size, void* d_ws, size_t ws_size,
                              hipStream_t stream){
  const int* z    = (const int*)d_in[0];
  const void* pos = d_in[1];
  // d_in[2] cell, d_in[3] batch: numerically dead (sym == I)
  const int* ei   = (const int*)d_in[4];
  const void* emb   = d_in[5];
  const void* mnpW1 = d_in[6];
  const void* mnpb1 = d_in[7];
  const void* mnpW2 = d_in[8];
  const void* mnpb2 = d_in[9];
  const void* meW   = d_in[10];
  const void* em1W1 = d_in[11];
  const void* em1W2 = d_in[12];
  const void* em2W1 = d_in[13];
  const void* em2W2 = d_in[14];
  const void* euW   = d_in[15];

  float* base  = (float*)d_ws;
  int*   flag  = (int*)d_ws;            // 4 floats reserved
  float* atom   = base + 4;             // 1,280,000
  float* force  = atom  + NN*NF;        // 3,840,000
  float* fdelta = force + NN*3*NF;      // 3,840,000
  float* h1     = fdelta+ NN*3*NF;      // 1,280,000
  float* h      = h1    + NN*NF;        // 1,280,000
  float* dvals  = h     + NN*NF;        //   160,000
  float* dirv   = dvals + NE;           //   480,000
  float* wbuf   = dirv  + 3*NE;
  float* posf   = wbuf;                 //  30,000
  float* embf   = posf  + NN*3;         //  15,232
  float* mnpW1f = embf  + 119*NF;
  float* mnpb1f = mnpW1f+ 3*NF*NF;
  float* mnpW2f = mnpb1f+ 3*NF;
  float* mnpb2f = mnpW2f+ 3*NF*NF;
  float* meWf   = mnpb2f+ 3*NF;
  float* em1W1f = meWf  + 3*NB*NF;
  float* em1W2f = em1W1f+ 3*NF*NF;
  float* em2W1f = em1W2f+ 3*NF*NF;
  float* em2W2f = em2W1f+ 3*NF*NF;
  float* euWf   = em2W2f+ 3*NF*NF;
  unsigned short* mesw  = (unsigned short*)(euWf + 3*NF*NF);
  unsigned short* w11sw = mesw  + 3*4096;
  unsigned short* w12sw = w11sw + 3*16384;
  unsigned short* w21sw = w12sw + 3*16384;
  unsigned short* w22sw = w21sw + 3*16384;
  // int sort scratch
  int* count  = (int*)(w22sw + 3*16384);
  int* rowptr = count  + NN;            // NN+1
  int* cursor = rowptr + NN + 1;
  int* perm   = cursor + NN;            // NE

  k_detect<<<1, 256, 0, stream>>>(meW, 3*NB*NF, flag);

  #define CVT(src, dst, n) k_cvt<<<((n)+255)/256, 256, 0, stream>>>(src, dst, n, flag)
  CVT(pos,   posf,   NN*3);
  CVT(emb,   embf,   119*NF);
  CVT(mnpW1, mnpW1f, 3*NF*NF);
  CVT(mnpb1, mnpb1f, 3*NF);
  CVT(mnpW2, mnpW2f, 3*NF*NF);
  CVT(mnpb2, mnpb2f, 3*NF);
  CVT(meW,   meWf,   3*NB*NF);
  CVT(em1W1, em1W1f, 3*NF*NF);
  CVT(em1W2, em1W2f, 3*NF*NF);
  CVT(em2W1, em2W1f, 3*NF*NF);
  CVT(em2W2, em2W2f, 3*NF*NF);
  CVT(euW,   euWf,   3*NF*NF);
  #undef CVT

  k_swzme <<<(3*4096 +255)/256, 256, 0, stream>>>(meWf,   mesw);
  k_swz128<<<(3*16384+255)/256, 256, 0, stream>>>(em1W1f, w11sw);
  k_swz128<<<(3*16384+255)/256, 256, 0, stream>>>(em1W2f, w12sw);
  k_swz128<<<(3*16384+255)/256, 256, 0, stream>>>(em2W1f, w21sw);
  k_swz128<<<(3*16384+255)/256, 256, 0, stream>>>(em2W2f, w22sw);

  // counting sort of edges by destination i
  hipMemsetAsync(count, 0, NN*sizeof(int), stream);
  k_hist   <<<(NE+255)/256, 256, 0, stream>>>(ei, count);
  k_scan   <<<1, 256, 0, stream>>>(count, rowptr, cursor);
  k_scatter<<<(NE+255)/256, 256, 0, stream>>>(ei, cursor, perm);

  hipMemsetAsync(force, 0, (size_t)NN*3*NF*sizeof(float), stream);
  k_init_atom<<<(NN*NF+255)/256, 256, 0, stream>>>(z, embf, atom);
  k_edge_embed<<<(NE+255)/256, 256, 0, stream>>>(ei, posf, dvals, dirv);

  for (int l = 0; l < 3; l++){
    k_node_mlp<<<(NN+15)/16, 128, 0, stream>>>(atom, mnpW1f + (size_t)l*NF*NF, mnpb1f + (size_t)l*NF, h1, 1);
    k_node_mlp<<<(NN+15)/16, 128, 0, stream>>>(h1,   mnpW2f + (size_t)l*NF*NF, mnpb2f + (size_t)l*NF, h,  0);
    hipMemsetAsync(fdelta, 0, (size_t)NN*3*NF*sizeof(float), stream);
    k_edge_mfma<<<NE/16, 64, 0, stream>>>(ei, perm, dvals, dirv, h,
        mesw  + (size_t)l*4096,
        w11sw + (size_t)l*16384, w12sw + (size_t)l*16384,
        w21sw + (size_t)l*16384, w22sw + (size_t)l*16384,
        atom, force, fdelta);
    k_node_update<<<(NN+7)/8, 128, 0, stream>>>(force, fdelta, euWf + (size_t)l*NF*NF, atom);
  }

  k_writeout<<<(NN*NF + NN*3*NF + 255)/256, 256, 0, stream>>>(atom, force, d_out, flag);
}

// Round 5
// 980.293 us; speedup vs baseline: 2.7184x; 1.2777x over previous
//
#include <hip/hip_runtime.h>
#include <hip/hip_bf16.h>
#include <math.h>

#define NN 10000
#define NE 160000
#define NF 128
#define NB 20
#define CUT 5.0f
#define TP 132   // padded tile stride (floats), multiple of 4 for float4 LDS reads

typedef __attribute__((ext_vector_type(8))) short short8;
typedef __attribute__((ext_vector_type(4))) float floatx4;

__device__ __forceinline__ unsigned short f2b(float x){
  union { __hip_bfloat16 b; unsigned short u; } cv;
  cv.b = __float2bfloat16(x);
  return cv.u;
}
__device__ __forceinline__ float fast_silu(float v){
  return v * __builtin_amdgcn_rcpf(1.f + __expf(-v));
}

// ---------------- dtype detector: 1=bf16, 0=fp32 ----------------
__global__ __launch_bounds__(256) void k_detect(const void* __restrict__ w, int nelem,
                                                int* __restrict__ flag){
  __shared__ int cnt;
  if (threadIdx.x == 0) cnt = 0;
  __syncthreads();
  const unsigned short* hw = (const unsigned short*)w;
  int local = 0;
  for (int k = threadIdx.x; k < nelem; k += 256){
    unsigned short h = hw[k];
    int e = (h >> 7) & 0xFF;
    if ((h & 0x7FFF) == 0 || (e >= 103 && e <= 130)) local++;
  }
  atomicAdd(&cnt, local);
  __syncthreads();
  if (threadIdx.x == 0) *flag = (cnt >= (nelem * 9) / 10) ? 1 : 0;
}

// ---------------- generic convert-to-fp32 ----------------
__global__ __launch_bounds__(256) void k_cvt(const void* __restrict__ src, float* __restrict__ dst,
                                             int n, const int* __restrict__ flag){
  int i = blockIdx.x * 256 + threadIdx.x;
  if (i >= n) return;
  int isb = *flag;
  dst[i] = isb ? __bfloat162float(((const __hip_bfloat16*)src)[i])
               : ((const float*)src)[i];
}

// ---------------- counting sort of edges by destination i ----------------
__global__ __launch_bounds__(256) void k_hist(const int* __restrict__ ei, int* __restrict__ count){
  int e = blockIdx.x*256 + threadIdx.x;
  if (e < NE) atomicAdd(&count[ei[e]], 1);
}
__global__ __launch_bounds__(256) void k_scan(const int* __restrict__ count,
                                              int* __restrict__ rowptr, int* __restrict__ cursor){
  __shared__ int part[256];
  const int CH = (NN + 255) / 256;
  int t = threadIdx.x;
  int base = t * CH;
  int s = 0;
  for (int k = 0; k < CH; k++){ int i = base + k; if (i < NN) s += count[i]; }
  part[t] = s;
  __syncthreads();
  for (int off = 1; off < 256; off <<= 1){
    int v = (t >= off) ? part[t - off] : 0;
    __syncthreads();
    part[t] += v;
    __syncthreads();
  }
  int run = (t == 0) ? 0 : part[t - 1];
  for (int k = 0; k < CH; k++){
    int i = base + k;
    if (i < NN){ rowptr[i] = run; cursor[i] = run; run += count[i]; }
  }
  if (t == 255) rowptr[NN] = run;
}
__global__ __launch_bounds__(256) void k_scatter(const int* __restrict__ ei,
                                                 int* __restrict__ cursor, int* __restrict__ perm){
  int e = blockIdx.x*256 + threadIdx.x;
  if (e >= NE) return;
  int pos = atomicAdd(&cursor[ei[e]], 1);
  perm[pos] = e;
}

// ---------------- weight swizzle to MFMA B-fragment layout ----------------
__global__ __launch_bounds__(256) void k_swz128(const float* __restrict__ W, unsigned short* __restrict__ out){
  int idx = blockIdx.x*256 + threadIdx.x;     // 3*16384
  if (idx >= 3*16384) return;
  int l = idx >> 14, rem = idx & 16383;
  int j = rem & 7, lane = (rem >> 3) & 63, tn = (rem >> 9) & 7, tk = rem >> 12;
  int k = tk*32 + ((lane >> 4) & 3)*8 + j, n = tn*16 + (lane & 15);
  out[idx] = f2b(W[l*16384 + k*NF + n]);
}
__global__ __launch_bounds__(256) void k_swzme(const float* __restrict__ W, unsigned short* __restrict__ out){
  int idx = blockIdx.x*256 + threadIdx.x;     // 3*4096
  if (idx >= 3*4096) return;
  int l = idx >> 12, rem = idx & 4095;
  int j = rem & 7, lane = (rem >> 3) & 63, tn = rem >> 9;
  int k = ((lane >> 4) & 3)*8 + j, n = tn*16 + (lane & 15);
  out[idx] = (k < NB) ? f2b(W[l*NB*NF + k*NF + n]) : (unsigned short)0;
}

// ---------------- init ----------------
__global__ __launch_bounds__(256) void k_init_atom(const int* __restrict__ z,
                                                   const float* __restrict__ emb,
                                                   float* __restrict__ atom){
  int idx = blockIdx.x * 256 + threadIdx.x;
  if (idx >= NN * NF) return;
  int n = idx >> 7, f = idx & (NF - 1);
  atom[idx] = emb[z[n] * NF + f];
}

// ---------------- edge embedding into SORTED slots ----------------
__global__ __launch_bounds__(256) void k_edge_embed(const int* __restrict__ ei,
                                                    const int* __restrict__ perm,
                                                    const float* __restrict__ pos,
                                                    int* __restrict__ iis, int* __restrict__ jjs,
                                                    float* __restrict__ ds, float* __restrict__ dirs){
  int s = blockIdx.x * 256 + threadIdx.x;
  if (s >= NE) return;
  int e = perm[s];
  int i = ei[e], j = ei[NE + e];
  float dx = pos[j*3+0] - pos[i*3+0];
  float dy = pos[j*3+1] - pos[i*3+1];
  float dz = pos[j*3+2] - pos[i*3+2];
  float d = sqrtf(dx*dx + dy*dy + dz*dz + 1e-12f);
  float inv = 1.0f / d;
  iis[s] = i; jjs[s] = j;
  ds[s] = d;
  dirs[s*3+0] = dx*inv; dirs[s*3+1] = dy*inv; dirs[s*3+2] = dz*inv;
}

// ---------------- node MLP ----------------
__global__ __launch_bounds__(128) void k_node_mlp(const float* __restrict__ in,
                                                  const float* __restrict__ W,
                                                  const float* __restrict__ b,
                                                  float* __restrict__ out, int apply_silu){
  __shared__ float a_lds[16][NF];
  int f = threadIdx.x;
  int n0 = blockIdx.x * 16;
  #pragma unroll
  for (int nn = 0; nn < 16; nn++){
    int n = n0 + nn;
    a_lds[nn][f] = (n < NN) ? in[n*NF + f] : 0.f;
  }
  __syncthreads();
  float acc[16];
  #pragma unroll
  for (int nn = 0; nn < 16; nn++) acc[nn] = 0.f;
  #pragma unroll 4
  for (int k = 0; k < NF; k++){
    float w = W[k*NF + f];
    #pragma unroll
    for (int nn = 0; nn < 16; nn++) acc[nn] += a_lds[nn][k] * w;
  }
  float bias = b[f];
  #pragma unroll
  for (int nn = 0; nn < 16; nn++){
    int n = n0 + nn;
    if (n < NN){
      float v = acc[nn] + bias;
      if (apply_silu) v = fast_silu(v);
      out[n*NF + f] = v;
    }
  }
}

// ---------------- MFMA edge kernel: 1 wave/16 sorted edges, single fp32 LDS tile ----------------
__global__ __launch_bounds__(64, 4) void k_edge_mfma(
    const int* __restrict__ iis, const int* __restrict__ jjs,
    const float* __restrict__ ds, const float* __restrict__ dirs,
    const float* __restrict__ h,
    const unsigned short* __restrict__ mesw,
    const unsigned short* __restrict__ w11sw, const unsigned short* __restrict__ w12sw,
    const unsigned short* __restrict__ w21sw, const unsigned short* __restrict__ w22sw,
    float* __restrict__ atom, const float* __restrict__ force, float* __restrict__ fdelta)
{
  __shared__ __align__(16) float tile[16][TP];
  __shared__ int iiS[16];

  const int lane = threadIdx.x;
  const int q    = lane >> 4;
  const int ln   = lane & 15;
  const int e0   = blockIdx.x * 16;   // grid = NE/16 exactly

  if (lane < 16) iiS[lane] = iis[e0 + lane];

  int iiR[4], jjR[4];
  float dirR[4][3];
  #pragma unroll
  for (int r = 0; r < 4; r++){
    int s = e0 + q*4 + r;
    iiR[r] = iis[s]; jjR[r] = jjs[s];
    dirR[r][0] = dirs[s*3+0]; dirR[r][1] = dirs[s*3+1]; dirR[r][2] = dirs[s*3+2];
  }

  // A-fragment of rbf: lane holds sorted edge m=ln, k=q*8+j (K padded 20->32)
  float dA  = ds[e0 + ln];
  float fcA = (dA < CUT) ? 0.5f*(cosf((float)M_PI*dA*(1.0f/CUT)) + 1.0f) : 0.0f;
  short8 a_rbf;
  #pragma unroll
  for (int j = 0; j < 8; j++){
    int k = q*8 + j;
    float v = 0.f;
    if (k < NB){
      float t = (dA - CUT*(float)k/(float)(NB-1)) * ((float)NB/CUT);
      v = __expf(-t*t) * fcA;
    }
    a_rbf[j] = (short)f2b(v);
  }

  // me = rbf @ meW; msg = me*h[i]*h[j] -> tile (fp32)
  #pragma unroll
  for (int tn = 0; tn < 8; tn++){
    short8 b = *(const short8*)(mesw + (size_t)(tn*64 + lane)*8);
    floatx4 c = {0.f,0.f,0.f,0.f};
    c = __builtin_amdgcn_mfma_f32_16x16x32_bf16(a_rbf, b, c, 0, 0, 0);
    int n = tn*16 + ln;
    #pragma unroll
    for (int r = 0; r < 4; r++){
      tile[q*4 + r][n] = c[r] * h[iiR[r]*NF + n] * h[jjR[r]*NF + n];
    }
  }
  __syncthreads();

  // segment flush: atom[i] += sum of msg rows with destination i
  {
    int seg = 0;
    for (int m = 1; m <= 16; m++){
      if (m == 16 || iiS[m] != iiS[seg]){
        int ii = iiS[seg];
        for (int c = lane; c < NF; c += 64){
          float s = 0.f;
          for (int r = seg; r < m; r++) s += tile[r][c];
          atomicAdd(&atom[ii*NF + c], s);
        }
        seg = m;
      }
    }
  }

  // fused dual pass: c1 = msg @ w11, c2 = msg @ w21 (A-frags read from tile)
  floatx4 c1[8], c2[8];
  #pragma unroll
  for (int tn = 0; tn < 8; tn++){ c1[tn] = (floatx4){0,0,0,0}; c2[tn] = (floatx4){0,0,0,0}; }
  #pragma unroll
  for (int tk = 0; tk < 4; tk++){
    const float4 u0 = *(const float4*)&tile[ln][tk*32 + q*8];
    const float4 u1 = *(const float4*)&tile[ln][tk*32 + q*8 + 4];
    short8 a;
    a[0]=(short)f2b(u0.x); a[1]=(short)f2b(u0.y); a[2]=(short)f2b(u0.z); a[3]=(short)f2b(u0.w);
    a[4]=(short)f2b(u1.x); a[5]=(short)f2b(u1.y); a[6]=(short)f2b(u1.z); a[7]=(short)f2b(u1.w);
    #pragma unroll
    for (int tn = 0; tn < 8; tn++){
      short8 b1 = *(const short8*)(w11sw + (size_t)((tk*8 + tn)*64 + lane)*8);
      c1[tn] = __builtin_amdgcn_mfma_f32_16x16x32_bf16(a, b1, c1[tn], 0, 0, 0);
      short8 b2 = *(const short8*)(w21sw + (size_t)((tk*8 + tn)*64 + lane)*8);
      c2[tn] = __builtin_amdgcn_mfma_f32_16x16x32_bf16(a, b2, c2[tn], 0, 0, 0);
    }
  }
  __syncthreads();   // all tile reads done

  // t1 = silu(c1) -> tile; t2 = silu(c2) kept in regs
  #pragma unroll
  for (int tn = 0; tn < 8; tn++){
    int n = tn*16 + ln;
    #pragma unroll
    for (int r = 0; r < 4; r++){
      tile[q*4 + r][n] = fast_silu(c1[tn][r]);
      c2[tn][r] = fast_silu(c2[tn][r]);
    }
  }
  __syncthreads();

  // g1 = t1 @ w12
  floatx4 g1[8];
  #pragma unroll
  for (int tn = 0; tn < 8; tn++) g1[tn] = (floatx4){0,0,0,0};
  #pragma unroll
  for (int tk = 0; tk < 4; tk++){
    const float4 u0 = *(const float4*)&tile[ln][tk*32 + q*8];
    const float4 u1 = *(const float4*)&tile[ln][tk*32 + q*8 + 4];
    short8 a;
    a[0]=(short)f2b(u0.x); a[1]=(short)f2b(u0.y); a[2]=(short)f2b(u0.z); a[3]=(short)f2b(u0.w);
    a[4]=(short)f2b(u1.x); a[5]=(short)f2b(u1.y); a[6]=(short)f2b(u1.z); a[7]=(short)f2b(u1.w);
    #pragma unroll
    for (int tn = 0; tn < 8; tn++){
      short8 b = *(const short8*)(w12sw + (size_t)((tk*8 + tn)*64 + lane)*8);
      g1[tn] = __builtin_amdgcn_mfma_f32_16x16x32_bf16(a, b, g1[tn], 0, 0, 0);
    }
  }
  __syncthreads();

  // t2 -> tile
  #pragma unroll
  for (int tn = 0; tn < 8; tn++){
    int n = tn*16 + ln;
    #pragma unroll
    for (int r = 0; r < 4; r++) tile[q*4 + r][n] = c2[tn][r];
  }
  __syncthreads();

  // g2 = t2 @ w22 (reuse c1 as accumulator)
  #pragma unroll
  for (int tn = 0; tn < 8; tn++) c1[tn] = (floatx4){0,0,0,0};
  #pragma unroll
  for (int tk = 0; tk < 4; tk++){
    const float4 u0 = *(const float4*)&tile[ln][tk*32 + q*8];
    const float4 u1 = *(const float4*)&tile[ln][tk*32 + q*8 + 4];
    short8 a;
    a[0]=(short)f2b(u0.x); a[1]=(short)f2b(u0.y); a[2]=(short)f2b(u0.z); a[3]=(short)f2b(u0.w);
    a[4]=(short)f2b(u1.x); a[5]=(short)f2b(u1.y); a[6]=(short)f2b(u1.z); a[7]=(short)f2b(u1.w);
    #pragma unroll
    for (int tn = 0; tn < 8; tn++){
      short8 b = *(const short8*)(w22sw + (size_t)((tk*8 + tn)*64 + lane)*8);
      c1[tn] = __builtin_amdgcn_mfma_f32_16x16x32_bf16(a, b, c1[tn], 0, 0, 0);
    }
  }

  // three d-passes: tile <- g1*dir + g2*force_old[j]; segment flush into fdelta
  for (int d = 0; d < 3; d++){
    __syncthreads();
    #pragma unroll
    for (int tn = 0; tn < 8; tn++){
      int n = tn*16 + ln;
      #pragma unroll
      for (int r = 0; r < 4; r++){
        tile[q*4 + r][n] = g1[tn][r]*dirR[r][d] + c1[tn][r]*force[jjR[r]*(3*NF) + d*NF + n];
      }
    }
    __syncthreads();
    int seg = 0;
    for (int m = 1; m <= 16; m++){
      if (m == 16 || iiS[m] != iiS[seg]){
        int ii = iiS[seg];
        for (int c = lane; c < NF; c += 64){
          float s = 0.f;
          for (int r = seg; r < m; r++) s += tile[r][c];
          atomicAdd(&fdelta[ii*(3*NF) + d*NF + c], s);
        }
        seg = m;
      }
    }
  }
}

// ---------------- node update ----------------
__global__ __launch_bounds__(128) void k_node_update(
    float* __restrict__ force, const float* __restrict__ fdelta,
    const float* __restrict__ euW, float* __restrict__ atom){
  __shared__ float fl[8][3][NF];
  int f = threadIdx.x;
  int n0 = blockIdx.x * 8;
  #pragma unroll
  for (int nn = 0; nn < 8; nn++){
    int n = n0 + nn;
    #pragma unroll
    for (int d = 0; d < 3; d++){
      if (n < NN){
        int idx = n*(3*NF) + d*NF + f;
        float v = force[idx] + fdelta[idx];
        force[idx] = v;
        fl[nn][d][f] = v;
      } else fl[nn][d][f] = 0.f;
    }
  }
  __syncthreads();
  float acc[8][3];
  #pragma unroll
  for (int nn = 0; nn < 8; nn++)
    #pragma unroll
    for (int d = 0; d < 3; d++) acc[nn][d] = 0.f;
  #pragma unroll 4
  for (int k = 0; k < NF; k++){
    float w = euW[k*NF + f];
    #pragma unroll
    for (int nn = 0; nn < 8; nn++)
      #pragma unroll
      for (int d = 0; d < 3; d++) acc[nn][d] += fl[nn][d][k] * w;
  }
  #pragma unroll
  for (int nn = 0; nn < 8; nn++){
    int n = n0 + nn;
    if (n >= NN) continue;
    float s = 0.f;
    #pragma unroll
    for (int d = 0; d < 3; d++) s += fl[nn][d][f] * acc[nn][d];
    atom[n*NF + f] += s;
  }
}

// ---------------- write out ----------------
__global__ __launch_bounds__(256) void k_writeout(const float* __restrict__ atom,
                                                  const float* __restrict__ force,
                                                  void* __restrict__ out,
                                                  const int* __restrict__ flag){
  int idx = blockIdx.x * 256 + threadIdx.x;
  const int na = NN * NF;
  const int tot = na + NN * 3 * NF;
  if (idx >= tot) return;
  float v = (idx < na) ? atom[idx] : force[idx - na];
  if (*flag) ((__hip_bfloat16*)out)[idx] = __float2bfloat16(v);
  else       ((float*)out)[idx] = v;
}

extern "C" void kernel_launch(void* const* d_in, const int* in_sizes, int n_in,
                              void* d_out, int out_size, void* d_ws, size_t ws_size,
                              hipStream_t stream){
  const int* z    = (const int*)d_in[0];
  const void* pos = d_in[1];
  // d_in[2] cell, d_in[3] batch: numerically dead (sym == I)
  const int* ei   = (const int*)d_in[4];
  const void* emb   = d_in[5];
  const void* mnpW1 = d_in[6];
  const void* mnpb1 = d_in[7];
  const void* mnpW2 = d_in[8];
  const void* mnpb2 = d_in[9];
  const void* meW   = d_in[10];
  const void* em1W1 = d_in[11];
  const void* em1W2 = d_in[12];
  const void* em2W1 = d_in[13];
  const void* em2W2 = d_in[14];
  const void* euW   = d_in[15];

  float* base  = (float*)d_ws;
  int*   flag  = (int*)d_ws;            // 4 floats reserved
  float* atom   = base + 4;             // 1,280,000
  float* force  = atom  + NN*NF;        // 3,840,000
  float* fdelta = force + NN*3*NF;      // 3,840,000
  float* h1     = fdelta+ NN*3*NF;      // 1,280,000
  float* h      = h1    + NN*NF;        // 1,280,000
  float* ds     = h     + NN*NF;        //   160,000
  float* dirs   = ds    + NE;           //   480,000
  float* wbuf   = dirs  + 3*NE;
  float* posf   = wbuf;                 //  30,000
  float* embf   = posf  + NN*3;         //  15,232
  float* mnpW1f = embf  + 119*NF;
  float* mnpb1f = mnpW1f+ 3*NF*NF;
  float* mnpW2f = mnpb1f+ 3*NF;
  float* mnpb2f = mnpW2f+ 3*NF*NF;
  float* meWf   = mnpb2f+ 3*NF;
  float* em1W1f = meWf  + 3*NB*NF;
  float* em1W2f = em1W1f+ 3*NF*NF;
  float* em2W1f = em1W2f+ 3*NF*NF;
  float* em2W2f = em2W1f+ 3*NF*NF;
  float* euWf   = em2W2f+ 3*NF*NF;
  unsigned short* mesw  = (unsigned short*)(euWf + 3*NF*NF);
  unsigned short* w11sw = mesw  + 3*4096;
  unsigned short* w12sw = w11sw + 3*16384;
  unsigned short* w21sw = w12sw + 3*16384;
  unsigned short* w22sw = w21sw + 3*16384;
  // int sort scratch + sorted edge payloads
  int* count  = (int*)(w22sw + 3*16384);
  int* rowptr = count  + NN;            // NN+1
  int* cursor = rowptr + NN + 1;
  int* perm   = cursor + NN;            // NE
  int* iis    = perm   + NE;            // NE
  int* jjs    = iis    + NE;            // NE

  k_detect<<<1, 256, 0, stream>>>(meW, 3*NB*NF, flag);

  #define CVT(src, dst, n) k_cvt<<<((n)+255)/256, 256, 0, stream>>>(src, dst, n, flag)
  CVT(pos,   posf,   NN*3);
  CVT(emb,   embf,   119*NF);
  CVT(mnpW1, mnpW1f, 3*NF*NF);
  CVT(mnpb1, mnpb1f, 3*NF);
  CVT(mnpW2, mnpW2f, 3*NF*NF);
  CVT(mnpb2, mnpb2f, 3*NF);
  CVT(meW,   meWf,   3*NB*NF);
  CVT(em1W1, em1W1f, 3*NF*NF);
  CVT(em1W2, em1W2f, 3*NF*NF);
  CVT(em2W1, em2W1f, 3*NF*NF);
  CVT(em2W2, em2W2f, 3*NF*NF);
  CVT(euW,   euWf,   3*NF*NF);
  #undef CVT

  k_swzme <<<(3*4096 +255)/256, 256, 0, stream>>>(meWf,   mesw);
  k_swz128<<<(3*16384+255)/256, 256, 0, stream>>>(em1W1f, w11sw);
  k_swz128<<<(3*16384+255)/256, 256, 0, stream>>>(em1W2f, w12sw);
  k_swz128<<<(3*16384+255)/256, 256, 0, stream>>>(em2W1f, w21sw);
  k_swz128<<<(3*16384+255)/256, 256, 0, stream>>>(em2W2f, w22sw);

  // counting sort of edges by destination i; payloads gathered into sorted slots
  hipMemsetAsync(count, 0, NN*sizeof(int), stream);
  k_hist   <<<(NE+255)/256, 256, 0, stream>>>(ei, count);
  k_scan   <<<1, 256, 0, stream>>>(count, rowptr, cursor);
  k_scatter<<<(NE+255)/256, 256, 0, stream>>>(ei, cursor, perm);
  k_edge_embed<<<(NE+255)/256, 256, 0, stream>>>(ei, perm, posf, iis, jjs, ds, dirs);

  hipMemsetAsync(force, 0, (size_t)NN*3*NF*sizeof(float), stream);
  k_init_atom<<<(NN*NF+255)/256, 256, 0, stream>>>(z, embf, atom);

  for (int l = 0; l < 3; l++){
    k_node_mlp<<<(NN+15)/16, 128, 0, stream>>>(atom, mnpW1f + (size_t)l*NF*NF, mnpb1f + (size_t)l*NF, h1, 1);
    k_node_mlp<<<(NN+15)/16, 128, 0, stream>>>(h1,   mnpW2f + (size_t)l*NF*NF, mnpb2f + (size_t)l*NF, h,  0);
    hipMemsetAsync(fdelta, 0, (size_t)NN*3*NF*sizeof(float), stream);
    k_edge_mfma<<<NE/16, 64, 0, stream>>>(iis, jjs, ds, dirs, h,
        mesw  + (size_t)l*4096,
        w11sw + (size_t)l*16384, w12sw + (size_t)l*16384,
        w21sw + (size_t)l*16384, w22sw + (size_t)l*16384,
        atom, force, fdelta);
    k_node_update<<<(NN+7)/8, 128, 0, stream>>>(force, fdelta, euWf + (size_t)l*NF*NF, atom);
  }

  k_writeout<<<(NN*NF + NN*3*NF + 255)/256, 256, 0, stream>>>(atom, force, d_out, flag);
}

// Round 6
// 726.160 us; speedup vs baseline: 3.6698x; 1.3500x over previous
//
#include <hip/hip_runtime.h>
#include <hip/hip_bf16.h>
#include <math.h>

#define NN 10000
#define NE 160000
#define NF 128
#define NB 20
#define CUT 5.0f
#define TPS 136   // u16 tile row stride

typedef __attribute__((ext_vector_type(8))) short short8;
typedef __attribute__((ext_vector_type(4))) float floatx4;
typedef unsigned short u16;
typedef unsigned int u32;

__device__ __forceinline__ u16 f2b(float x){
  union { __hip_bfloat16 b; u16 u; } cv;
  cv.b = __float2bfloat16(x);
  return cv.u;
}
__device__ __forceinline__ float b2f_raw(u16 x){ return __uint_as_float((u32)x << 16); }
__device__ __forceinline__ float lo_bf(u32 w){ return __uint_as_float(w << 16); }
__device__ __forceinline__ float hi_bf(u32 w){ return __uint_as_float(w & 0xFFFF0000u); }
__device__ __forceinline__ u32 packbf(float lo, float hi){
  return ((u32)f2b(hi) << 16) | (u32)f2b(lo);
}
__device__ __forceinline__ float fast_silu(float v){
  return v * __builtin_amdgcn_rcpf(1.f + __expf(-v));
}
__device__ __forceinline__ float rdf(const void* p, size_t i, int isb){
  return isb ? __bfloat162float(((const __hip_bfloat16*)p)[i]) : ((const float*)p)[i];
}

// ---------------- dtype detector: 1=bf16, 0=fp32 ----------------
__global__ __launch_bounds__(256) void k_detect(const void* __restrict__ w, int nelem,
                                                int* __restrict__ flag){
  __shared__ int cnt;
  if (threadIdx.x == 0) cnt = 0;
  __syncthreads();
  const u16* hw = (const u16*)w;
  int local = 0;
  for (int k = threadIdx.x; k < nelem; k += 256){
    u16 h = hw[k];
    int e = (h >> 7) & 0xFF;
    if ((h & 0x7FFF) == 0 || (e >= 103 && e <= 130)) local++;
  }
  atomicAdd(&cnt, local);
  __syncthreads();
  if (threadIdx.x == 0) *flag = (cnt >= (nelem * 9) / 10) ? 1 : 0;
}

// ---------------- fused convert-to-fp32 (5 tensors) ----------------
struct CvtArgs { const void* src[5]; float* dst[5]; int n[5]; };
__global__ __launch_bounds__(256) void k_cvt5(CvtArgs a, const int* __restrict__ flag){
  int y = blockIdx.y;
  int isb = *flag;
  const void* s = a.src[y]; float* d = a.dst[y]; int n = a.n[y];
  for (int i = blockIdx.x*256 + threadIdx.x; i < n; i += gridDim.x*256)
    d[i] = rdf(s, i, isb);
}

// ---------------- fused weight swizzle (6 128x128 matrices, raw input) ----------------
struct SwzArgs { const void* src[6]; u16* dst[6]; };
__global__ __launch_bounds__(256) void k_swz6(SwzArgs a, const int* __restrict__ flag){
  int y = blockIdx.y;
  int isb = *flag;
  const void* s = a.src[y]; u16* d = a.dst[y];
  int idx = blockIdx.x*256 + threadIdx.x;        // 192 blocks * 256 = 49152 = 3*16384
  int l = idx >> 14, rem = idx & 16383;
  int j = rem & 7, lane = (rem >> 3) & 63, tn = (rem >> 9) & 7, tk = rem >> 12;
  int k = tk*32 + ((lane >> 4) & 3)*8 + j, n = tn*16 + (lane & 15);
  d[idx] = f2b(rdf(s, (size_t)l*16384 + k*NF + n, isb));
}
__global__ __launch_bounds__(256) void k_swzme(const void* __restrict__ W, u16* __restrict__ out,
                                               const int* __restrict__ flag){
  int idx = blockIdx.x*256 + threadIdx.x;     // 3*4096
  if (idx >= 3*4096) return;
  int isb = *flag;
  int l = idx >> 12, rem = idx & 4095;
  int j = rem & 7, lane = (rem >> 3) & 63, tn = rem >> 9;
  int k = ((lane >> 4) & 3)*8 + j, n = tn*16 + (lane & 15);
  out[idx] = (k < NB) ? f2b(rdf(W, (size_t)l*NB*NF + k*NF + n, isb)) : (u16)0;
}

// ---------------- counting sort of edges by destination i ----------------
__global__ __launch_bounds__(256) void k_hist(const int* __restrict__ ei, int* __restrict__ count){
  int e = blockIdx.x*256 + threadIdx.x;
  if (e < NE) atomicAdd(&count[ei[e]], 1);
}
__global__ __launch_bounds__(256) void k_scan(const int* __restrict__ count,
                                              int* __restrict__ rowptr, int* __restrict__ cursor){
  __shared__ int part[256];
  const int CH = (NN + 255) / 256;
  int t = threadIdx.x;
  int base = t * CH;
  int s = 0;
  for (int k = 0; k < CH; k++){ int i = base + k; if (i < NN) s += count[i]; }
  part[t] = s;
  __syncthreads();
  for (int off = 1; off < 256; off <<= 1){
    int v = (t >= off) ? part[t - off] : 0;
    __syncthreads();
    part[t] += v;
    __syncthreads();
  }
  int run = (t == 0) ? 0 : part[t - 1];
  for (int k = 0; k < CH; k++){
    int i = base + k;
    if (i < NN){ rowptr[i] = run; cursor[i] = run; run += count[i]; }
  }
  if (t == 255) rowptr[NN] = run;
}
__global__ __launch_bounds__(256) void k_scatter(const int* __restrict__ ei,
                                                 int* __restrict__ cursor, int* __restrict__ perm){
  int e = blockIdx.x*256 + threadIdx.x;
  if (e >= NE) return;
  int pos = atomicAdd(&cursor[ei[e]], 1);
  perm[pos] = e;
}

// ---------------- init atom ----------------
__global__ __launch_bounds__(256) void k_init_atom(const int* __restrict__ z,
                                                   const float* __restrict__ emb,
                                                   float* __restrict__ atom){
  int idx = blockIdx.x * 256 + threadIdx.x;
  if (idx >= NN * NF) return;
  int n = idx >> 7, f = idx & (NF - 1);
  atom[idx] = emb[z[n] * NF + f];
}

// ---------------- edge embedding into SORTED slots ----------------
__global__ __launch_bounds__(256) void k_edge_embed(const int* __restrict__ ei,
                                                    const int* __restrict__ perm,
                                                    const float* __restrict__ pos,
                                                    int* __restrict__ iis, int* __restrict__ jjs,
                                                    float* __restrict__ ds, float* __restrict__ dirs){
  int s = blockIdx.x * 256 + threadIdx.x;
  if (s >= NE) return;
  int e = perm[s];
  int i = ei[e], j = ei[NE + e];
  float dx = pos[j*3+0] - pos[i*3+0];
  float dy = pos[j*3+1] - pos[i*3+1];
  float dz = pos[j*3+2] - pos[i*3+2];
  float d = sqrtf(dx*dx + dy*dy + dz*dz + 1e-12f);
  float inv = 1.0f / d;
  iis[s] = i; jjs[s] = j;
  ds[s] = d;
  dirs[s*3+0] = dx*inv; dirs[s*3+1] = dy*inv; dirs[s*3+2] = dz*inv;
}

// ---------------- fused node MLP (MFMA): hb = (silu(atom@W1+b1))@W2+b2, paired bf16 ----------------
__global__ __launch_bounds__(64, 4) void k_node_mlp2(
    const float* __restrict__ atom,
    const u16* __restrict__ w1sw, const float* __restrict__ b1,
    const u16* __restrict__ w2sw, const float* __restrict__ b2,
    u32* __restrict__ hb)
{
  __shared__ __align__(16) u16 tileT[16][TPS];
  const int lane = threadIdx.x;
  const int q = lane >> 4, ln = lane & 15;
  const int n0 = blockIdx.x * 16;   // 625*16 = NN exactly

  floatx4 c1[8];
  #pragma unroll
  for (int tn = 0; tn < 8; tn++) c1[tn] = (floatx4){0,0,0,0};
  #pragma unroll
  for (int tk = 0; tk < 4; tk++){
    const float4 u0 = *(const float4*)&atom[(size_t)(n0+ln)*NF + tk*32 + q*8];
    const float4 u1 = *(const float4*)&atom[(size_t)(n0+ln)*NF + tk*32 + q*8 + 4];
    short8 a;
    a[0]=(short)f2b(u0.x); a[1]=(short)f2b(u0.y); a[2]=(short)f2b(u0.z); a[3]=(short)f2b(u0.w);
    a[4]=(short)f2b(u1.x); a[5]=(short)f2b(u1.y); a[6]=(short)f2b(u1.z); a[7]=(short)f2b(u1.w);
    #pragma unroll
    for (int tn = 0; tn < 8; tn++){
      short8 b = *(const short8*)(w1sw + (size_t)((tk*8 + tn)*64 + lane)*8);
      c1[tn] = __builtin_amdgcn_mfma_f32_16x16x32_bf16(a, b, c1[tn], 0, 0, 0);
    }
  }
  #pragma unroll
  for (int tn = 0; tn < 8; tn++){
    int n = tn*16 + ln;
    float bias = b1[n];
    #pragma unroll
    for (int r = 0; r < 4; r++)
      tileT[q*4 + r][n] = f2b(fast_silu(c1[tn][r] + bias));
  }
  __syncthreads();

  floatx4 c2[8];
  #pragma unroll
  for (int tn = 0; tn < 8; tn++) c2[tn] = (floatx4){0,0,0,0};
  #pragma unroll
  for (int tk = 0; tk < 4; tk++){
    short8 a = *(const short8*)&tileT[ln][tk*32 + q*8];
    #pragma unroll
    for (int tn = 0; tn < 8; tn++){
      short8 b = *(const short8*)(w2sw + (size_t)((tk*8 + tn)*64 + lane)*8);
      c2[tn] = __builtin_amdgcn_mfma_f32_16x16x32_bf16(a, b, c2[tn], 0, 0, 0);
    }
  }
  float b2n[8];
  #pragma unroll
  for (int tn = 0; tn < 8; tn++) b2n[tn] = b2[tn*16 + ln];
  #pragma unroll
  for (int tn = 0; tn < 4; tn++){
    #pragma unroll
    for (int r = 0; r < 4; r++){
      float vl = c2[tn][r]   + b2n[tn];
      float vh = c2[tn+4][r] + b2n[tn+4];
      hb[(size_t)(n0 + q*4 + r)*64 + tn*16 + ln] = packbf(vl, vh);
    }
  }
}

// ---------------- MFMA edge kernel: 1 wave/16 sorted edges, single bf16 LDS tile ----------------
__global__ __launch_bounds__(64, 4) void k_edge_mfma(
    const int* __restrict__ iis, const int* __restrict__ jjs,
    const float* __restrict__ ds, const float* __restrict__ dirs,
    const u32* __restrict__ hb,
    const u16* __restrict__ mesw,
    const u16* __restrict__ w11sw, const u16* __restrict__ w12sw,
    const u16* __restrict__ w21sw, const u16* __restrict__ w22sw,
    float* __restrict__ atom, const u32* __restrict__ forceb, float* __restrict__ fdelta)
{
  __shared__ __align__(16) u16 tileM[16][TPS];
  __shared__ int iiS[16];

  const int lane = threadIdx.x;
  const int q = lane >> 4, ln = lane & 15;
  const int e0 = blockIdx.x * 16;   // grid = NE/16 exactly

  if (lane < 16) iiS[lane] = iis[e0 + lane];

  int iiR[4], jjR[4];
  float dirR[4][3];
  #pragma unroll
  for (int r = 0; r < 4; r++){
    int s = e0 + q*4 + r;
    iiR[r] = iis[s]; jjR[r] = jjs[s];
    dirR[r][0] = dirs[s*3+0]; dirR[r][1] = dirs[s*3+1]; dirR[r][2] = dirs[s*3+2];
  }

  // paired h gathers: word t4 holds cols (t4*16+ln, +64) i.e. tn=t4 (lo) and tn=t4+4 (hi)
  u32 hiw[4][4], hjw[4][4];
  #pragma unroll
  for (int r = 0; r < 4; r++)
    #pragma unroll
    for (int t4 = 0; t4 < 4; t4++){
      hiw[r][t4] = hb[(size_t)iiR[r]*64 + t4*16 + ln];
      hjw[r][t4] = hb[(size_t)jjR[r]*64 + t4*16 + ln];
    }

  // rbf A-fragment (K padded 20->32)
  float dA  = ds[e0 + ln];
  float fcA = (dA < CUT) ? 0.5f*(cosf((float)M_PI*dA*(1.0f/CUT)) + 1.0f) : 0.0f;
  short8 a_rbf;
  #pragma unroll
  for (int j = 0; j < 8; j++){
    int k = q*8 + j;
    float v = 0.f;
    if (k < NB){
      float t = (dA - CUT*(float)k/(float)(NB-1)) * ((float)NB/CUT);
      v = __expf(-t*t) * fcA;
    }
    a_rbf[j] = (short)f2b(v);
  }

  // me = rbf @ meW; msg = me*h_i*h_j -> tileM (bf16)
  #pragma unroll
  for (int tn = 0; tn < 8; tn++){
    short8 b = *(const short8*)(mesw + (size_t)(tn*64 + lane)*8);
    floatx4 c = {0.f,0.f,0.f,0.f};
    c = __builtin_amdgcn_mfma_f32_16x16x32_bf16(a_rbf, b, c, 0, 0, 0);
    int n = tn*16 + ln;
    int t4 = tn & 3;
    #pragma unroll
    for (int r = 0; r < 4; r++){
      float hi_ = (tn < 4) ? lo_bf(hiw[r][t4]) : hi_bf(hiw[r][t4]);
      float hj_ = (tn < 4) ? lo_bf(hjw[r][t4]) : hi_bf(hjw[r][t4]);
      tileM[q*4 + r][n] = f2b(c[r] * hi_ * hj_);
    }
  }
  __syncthreads();

  // atom segment flush from tileM
  {
    int seg = 0;
    for (int m = 1; m <= 16; m++){
      if (m == 16 || iiS[m] != iiS[seg]){
        int ii = iiS[seg];
        for (int c = lane; c < NF; c += 64){
          float s = 0.f;
          for (int r = seg; r < m; r++) s += b2f_raw(tileM[r][c]);
          atomicAdd(&atom[(size_t)ii*NF + c], s);
        }
        seg = m;
      }
    }
  }

  // c2 = msg @ w21 (held in regs as t2 after silu)
  floatx4 c2[8];
  #pragma unroll
  for (int tn = 0; tn < 8; tn++) c2[tn] = (floatx4){0,0,0,0};
  #pragma unroll
  for (int tk = 0; tk < 4; tk++){
    short8 a = *(const short8*)&tileM[ln][tk*32 + q*8];
    #pragma unroll
    for (int tn = 0; tn < 8; tn++){
      short8 b = *(const short8*)(w21sw + (size_t)((tk*8 + tn)*64 + lane)*8);
      c2[tn] = __builtin_amdgcn_mfma_f32_16x16x32_bf16(a, b, c2[tn], 0, 0, 0);
    }
  }
  // c1 = msg @ w11
  floatx4 c1[8];
  #pragma unroll
  for (int tn = 0; tn < 8; tn++) c1[tn] = (floatx4){0,0,0,0};
  #pragma unroll
  for (int tk = 0; tk < 4; tk++){
    short8 a = *(const short8*)&tileM[ln][tk*32 + q*8];
    #pragma unroll
    for (int tn = 0; tn < 8; tn++){
      short8 b = *(const short8*)(w11sw + (size_t)((tk*8 + tn)*64 + lane)*8);
      c1[tn] = __builtin_amdgcn_mfma_f32_16x16x32_bf16(a, b, c1[tn], 0, 0, 0);
    }
  }
  __syncthreads();   // all tileM reads done
  // t1 -> tileM ; t2 = silu(c2) stays in regs
  #pragma unroll
  for (int tn = 0; tn < 8; tn++){
    int n = tn*16 + ln;
    #pragma unroll
    for (int r = 0; r < 4; r++){
      tileM[q*4 + r][n] = f2b(fast_silu(c1[tn][r]));
      c2[tn][r] = fast_silu(c2[tn][r]);
    }
  }
  __syncthreads();

  // g1 = t1 @ w12
  floatx4 g1[8];
  #pragma unroll
  for (int tn = 0; tn < 8; tn++) g1[tn] = (floatx4){0,0,0,0};
  #pragma unroll
  for (int tk = 0; tk < 4; tk++){
    short8 a = *(const short8*)&tileM[ln][tk*32 + q*8];
    #pragma unroll
    for (int tn = 0; tn < 8; tn++){
      short8 b = *(const short8*)(w12sw + (size_t)((tk*8 + tn)*64 + lane)*8);
      g1[tn] = __builtin_amdgcn_mfma_f32_16x16x32_bf16(a, b, g1[tn], 0, 0, 0);
    }
  }
  __syncthreads();
  // t2 -> tileM
  #pragma unroll
  for (int tn = 0; tn < 8; tn++){
    int n = tn*16 + ln;
    #pragma unroll
    for (int r = 0; r < 4; r++) tileM[q*4 + r][n] = f2b(c2[tn][r]);
  }
  __syncthreads();
  // g2 = t2 @ w22 (reuse c1)
  #pragma unroll
  for (int tn = 0; tn < 8; tn++) c1[tn] = (floatx4){0,0,0,0};
  #pragma unroll
  for (int tk = 0; tk < 4; tk++){
    short8 a = *(const short8*)&tileM[ln][tk*32 + q*8];
    #pragma unroll
    for (int tn = 0; tn < 8; tn++){
      short8 b = *(const short8*)(w22sw + (size_t)((tk*8 + tn)*64 + lane)*8);
      c1[tn] = __builtin_amdgcn_mfma_f32_16x16x32_bf16(a, b, c1[tn], 0, 0, 0);
    }
  }

  // three d-passes: tileM <- g1*dir + g2*force_old[j]; segment flush into fdelta
  for (int d = 0; d < 3; d++){
    __syncthreads();
    u32 fjw[4][4];
    #pragma unroll
    for (int r = 0; r < 4; r++)
      #pragma unroll
      for (int t4 = 0; t4 < 4; t4++)
        fjw[r][t4] = forceb[((size_t)jjR[r]*3 + d)*64 + t4*16 + ln];
    #pragma unroll
    for (int tn = 0; tn < 8; tn++){
      int n = tn*16 + ln;
      int t4 = tn & 3;
      #pragma unroll
      for (int r = 0; r < 4; r++){
        float fj = (tn < 4) ? lo_bf(fjw[r][t4]) : hi_bf(fjw[r][t4]);
        tileM[q*4 + r][n] = f2b(g1[tn][r]*dirR[r][d] + c1[tn][r]*fj);
      }
    }
    __syncthreads();
    int seg = 0;
    for (int m = 1; m <= 16; m++){
      if (m == 16 || iiS[m] != iiS[seg]){
        int ii = iiS[seg];
        for (int c = lane; c < NF; c += 64){
          float s = 0.f;
          for (int r = seg; r < m; r++) s += b2f_raw(tileM[r][c]);
          atomicAdd(&fdelta[((size_t)ii*3 + d)*NF + c], s);
        }
        seg = m;
      }
    }
  }
}

// ---------------- node update: force += fdelta (and zero fdelta), mirror forceb, eu term ----------------
__global__ __launch_bounds__(128) void k_node_update(
    float* __restrict__ force, float* __restrict__ fdelta,
    const float* __restrict__ euW, float* __restrict__ atom,
    u32* __restrict__ forceb){
  __shared__ float fl[8][3][NF];
  int f = threadIdx.x;
  int n0 = blockIdx.x * 8;
  #pragma unroll
  for (int nn = 0; nn < 8; nn++){
    int n = n0 + nn;
    #pragma unroll
    for (int d = 0; d < 3; d++){
      if (n < NN){
        size_t idx = ((size_t)n*3 + d)*NF + f;
        float v = force[idx] + fdelta[idx];
        force[idx] = v;
        fdelta[idx] = 0.f;          // ready for next layer
        fl[nn][d][f] = v;
      } else fl[nn][d][f] = 0.f;
    }
  }
  __syncthreads();
  float acc[8][3];
  #pragma unroll
  for (int nn = 0; nn < 8; nn++)
    #pragma unroll
    for (int d = 0; d < 3; d++) acc[nn][d] = 0.f;
  #pragma unroll 4
  for (int k = 0; k < NF; k++){
    float w = euW[k*NF + f];
    #pragma unroll
    for (int nn = 0; nn < 8; nn++)
      #pragma unroll
      for (int d = 0; d < 3; d++) acc[nn][d] += fl[nn][d][k] * w;
  }
  #pragma unroll
  for (int nn = 0; nn < 8; nn++){
    int n = n0 + nn;
    if (n >= NN) continue;
    float s = 0.f;
    #pragma unroll
    for (int d = 0; d < 3; d++) s += fl[nn][d][f] * acc[nn][d];
    atom[(size_t)n*NF + f] += s;
  }
  // paired-bf16 force mirror
  if (f < 64){
    #pragma unroll
    for (int nn = 0; nn < 8; nn++){
      int n = n0 + nn;
      if (n >= NN) continue;
      #pragma unroll
      for (int d = 0; d < 3; d++)
        forceb[((size_t)n*3 + d)*64 + f] = packbf(fl[nn][d][f], fl[nn][d][f + 64]);
    }
  }
}

// ---------------- write out ----------------
__global__ __launch_bounds__(256) void k_writeout(const float* __restrict__ atom,
                                                  const float* __restrict__ force,
                                                  void* __restrict__ out,
                                                  const int* __restrict__ flag){
  int idx = blockIdx.x * 256 + threadIdx.x;
  const int na = NN * NF;
  const int tot = na + NN * 3 * NF;
  if (idx >= tot) return;
  float v = (idx < na) ? atom[idx] : force[idx - na];
  if (*flag) ((__hip_bfloat16*)out)[idx] = __float2bfloat16(v);
  else       ((float*)out)[idx] = v;
}

extern "C" void kernel_launch(void* const* d_in, const int* in_sizes, int n_in,
                              void* d_out, int out_size, void* d_ws, size_t ws_size,
                              hipStream_t stream){
  const int* z    = (const int*)d_in[0];
  const void* pos = d_in[1];
  // d_in[2] cell, d_in[3] batch: numerically dead (sym == I)
  const int* ei   = (const int*)d_in[4];
  const void* emb   = d_in[5];
  const void* mnpW1 = d_in[6];
  const void* mnpb1 = d_in[7];
  const void* mnpW2 = d_in[8];
  const void* mnpb2 = d_in[9];
  const void* meW   = d_in[10];
  const void* em1W1 = d_in[11];
  const void* em1W2 = d_in[12];
  const void* em2W1 = d_in[13];
  const void* em2W2 = d_in[14];
  const void* euW   = d_in[15];

  float* base  = (float*)d_ws;
  int*   flag  = (int*)d_ws;                  // 4 floats reserved
  float* atom   = base + 4;                   // NN*NF
  float* force  = atom   + NN*NF;             // NN*3*NF
  float* fdelta = force  + (size_t)NN*3*NF;   // NN*3*NF
  u32*   forceb = (u32*)(fdelta + (size_t)NN*3*NF);  // NN*3*64
  int*   count  = (int*)(forceb + (size_t)NN*3*64);  // NN
  // single memset zeroes force, fdelta, forceb, count (contiguous)
  float* ds    = (float*)(count + NN);
  float* dirs  = ds + NE;
  float* posf  = dirs + 3*NE;
  float* embf  = posf + NN*3;
  float* b1f   = embf + 119*NF;               // 3*NF
  float* b2f_  = b1f + 3*NF;                  // 3*NF
  float* euWf  = b2f_ + 3*NF;                 // 3*NF*NF
  u32*   hb    = (u32*)(euWf + 3*NF*NF);      // NN*64
  u16*   mesw  = (u16*)(hb + (size_t)NN*64);  // 3*4096
  u16*   w11sw = mesw  + 3*4096;
  u16*   w12sw = w11sw + 3*16384;
  u16*   w21sw = w12sw + 3*16384;
  u16*   w22sw = w21sw + 3*16384;
  u16*   w1sw  = w22sw + 3*16384;
  u16*   w2sw  = w1sw  + 3*16384;
  int* rowptr  = (int*)(w2sw + 3*16384);      // NN+1
  int* cursor  = rowptr + NN + 1;
  int* perm    = cursor + NN;                 // NE
  int* iis     = perm + NE;
  int* jjs     = iis + NE;

  k_detect<<<1, 256, 0, stream>>>(meW, 3*NB*NF, flag);

  // zero force + fdelta + forceb + count in one shot
  hipMemsetAsync(force, 0, ((size_t)NN*3*NF*2 + (size_t)NN*3*64 + NN)*4, stream);

  CvtArgs ca;
  ca.src[0]=pos;   ca.dst[0]=posf; ca.n[0]=NN*3;
  ca.src[1]=emb;   ca.dst[1]=embf; ca.n[1]=119*NF;
  ca.src[2]=mnpb1; ca.dst[2]=b1f;  ca.n[2]=3*NF;
  ca.src[3]=mnpb2; ca.dst[3]=b2f_; ca.n[3]=3*NF;
  ca.src[4]=euW;   ca.dst[4]=euWf; ca.n[4]=3*NF*NF;
  k_cvt5<<<dim3(120,5), 256, 0, stream>>>(ca, flag);

  SwzArgs sa;
  sa.src[0]=em1W1; sa.dst[0]=w11sw;
  sa.src[1]=em1W2; sa.dst[1]=w12sw;
  sa.src[2]=em2W1; sa.dst[2]=w21sw;
  sa.src[3]=em2W2; sa.dst[3]=w22sw;
  sa.src[4]=mnpW1; sa.dst[4]=w1sw;
  sa.src[5]=mnpW2; sa.dst[5]=w2sw;
  k_swz6 <<<dim3(192,6), 256, 0, stream>>>(sa, flag);
  k_swzme<<<(3*4096+255)/256, 256, 0, stream>>>(meW, mesw, flag);

  k_hist   <<<(NE+255)/256, 256, 0, stream>>>(ei, count);
  k_scan   <<<1, 256, 0, stream>>>(count, rowptr, cursor);
  k_scatter<<<(NE+255)/256, 256, 0, stream>>>(ei, cursor, perm);
  k_edge_embed<<<(NE+255)/256, 256, 0, stream>>>(ei, perm, posf, iis, jjs, ds, dirs);
  k_init_atom<<<(NN*NF+255)/256, 256, 0, stream>>>(z, embf, atom);

  for (int l = 0; l < 3; l++){
    k_node_mlp2<<<NN/16, 64, 0, stream>>>(atom,
        w1sw + (size_t)l*16384, b1f + (size_t)l*NF,
        w2sw + (size_t)l*16384, b2f_ + (size_t)l*NF, hb);
    k_edge_mfma<<<NE/16, 64, 0, stream>>>(iis, jjs, ds, dirs, hb,
        mesw  + (size_t)l*4096,
        w11sw + (size_t)l*16384, w12sw + (size_t)l*16384,
        w21sw + (size_t)l*16384, w22sw + (size_t)l*16384,
        atom, forceb, fdelta);
    k_node_update<<<(NN+7)/8, 128, 0, stream>>>(force, fdelta, euWf + (size_t)l*NF*NF, atom, forceb);
  }

  k_writeout<<<(NN*NF + NN*3*NF + 255)/256, 256, 0, stream>>>(atom, force, d_out, flag);
}